// Round 1
// baseline (3350.759 us; speedup 1.0000x reference)
//
#include <hip/hip_runtime.h>

// irreps: node = 64x0e + 32x1o (160 f32), edge = 8x0e + 8x1o (32 f32)
// hidden = 96x0e + 32x1o ; agg row = 96 scalars + 32x3 vectors = 192 f32
constexpr int kNodes  = 10000;
constexpr int kEdges  = 100000;
constexpr int NF_DIM  = 160;
constexpr int EA_DIM  = 32;
constexpr int AGG_DIM = 192;

constexpr float INV_SQRT3    = 0.57735026918962576f;   // w3j(1,1,0)
constexpr float INV_SQRT768  = 0.036084391824351615f;  // msg fan (64*8+32*8)
constexpr float INV_SQRT7168 = 0.011811389781538352f;  // upd scalar fan (64*96+32*32)
constexpr float INV_SQRT5120 = 0.013975424859373686f;  // upd vector fan (64*32+32*96)
constexpr float INV_SQRT32   = 0.17677669529663687f;

__device__ __forceinline__ float fsigmoid(float x) { return 1.0f / (1.0f + __expf(-x)); }
__device__ __forceinline__ float fsilu(float x)    { return x / (1.0f + __expf(-x)); }

// ============================ message kernel ============================
// 32 edges/block, 256 threads. FCTP(ns[col], es) -> gate -> linear ->
// atomicAdd scatter into agg[row][192]. GEMM form: A[e][k] built on the fly,
// k-ordering == e3nn weight flattening (k = u*8+v), weights staged pre-scaled.
__global__ __launch_bounds__(256, 2) void msg_kernel(
    const float* __restrict__ nf, const float* __restrict__ ea,
    const float* __restrict__ Wss, const float* __restrict__ Wvv,
    const float* __restrict__ Wsv, const float* __restrict__ Wvs,
    const float* __restrict__ Wls, const float* __restrict__ Wlv,
    const int* __restrict__ eidx, float* __restrict__ agg)
{
    constexpr int ET = 32, KT = 64;
    __shared__ float nf_sh[ET][161];   // +1 pad: stride 160 % 32 == 0 otherwise
    __shared__ float ea_sh[ET][33];
    __shared__ int   row_sh[ET];
    __shared__ float pool[11296];
    float* const ms_sh = pool;         // [32][97]  persists across both passes
    float* const As    = pool + 3104;  // scalar pass: [64][32]
    float* const W1    = pool + 5152;  //              [64][96]
    float* const Av    = pool + 3104;  // vector pass: [3][64][32]
    float* const W2    = pool + 9248;  //              [64][32]
    float* const pv_sh = pool + 3104;  // epilogue: gated vectors [32][97]
    float* const pl_sh = pool + 6208;  //           silu scalars  [32][65]

    const int t = threadIdx.x;
    const int eblk = blockIdx.x * ET;  // kEdges % 32 == 0: no tail

    { // stage gathered source-node rows + edge attrs (L2-served gather)
        const int i = t >> 3, j = t & 7;
        const int e = eblk + i;
        const int col = eidx[kEdges + e];
        if (j == 0) row_sh[i] = eidx[e];
        const float* src = nf + (size_t)col * NF_DIM;
        for (int c = j; c < NF_DIM; c += 8) nf_sh[i][c] = src[c];
        const float* esrc = ea + (size_t)e * EA_DIM;
        for (int c = j; c < EA_DIM; c += 8) ea_sh[i][c] = esrc[c];
    }
    __syncthreads();

    // ---- scalar path: ms[e][w<96] = sum_{k<768} A[e][k] * Wcat[k][w]
    //      k<512: xs[u]*ys[v] (k=u*8+v) ; k>=512: dot(xv[u],yv[v]) * 1/sqrt3
    float accS[2][6] = {};
    const int eS = 2 * (t >> 4);   // micro-tile: 2 edges x 6 outputs
    const int wS = 6 * (t & 15);
    for (int kt = 0; kt < 768; kt += KT) {
        for (int idx = t; idx < KT * ET; idx += 256) {
            const int kk = idx >> 5, e = idx & 31, k = kt + kk;
            float v;
            if (k < 512) {
                v = nf_sh[e][k >> 3] * ea_sh[e][k & 7];
            } else {
                const int r = k - 512;
                const float* xv = &nf_sh[e][64 + 3 * (r >> 3)];
                const float* yv = &ea_sh[e][8 + 3 * (r & 7)];
                v = xv[0] * yv[0] + xv[1] * yv[1] + xv[2] * yv[2];
            }
            As[kk * ET + e] = v;
        }
        for (int idx = t; idx < KT * 96; idx += 256) {
            const int kk = idx / 96, w = idx - kk * 96, k = kt + kk;
            const float wv = (k < 512) ? Wss[(size_t)k * 96 + w]
                                       : Wvv[(size_t)(k - 512) * 96 + w] * INV_SQRT3;
            W1[kk * 96 + w] = wv * INV_SQRT768;
        }
        __syncthreads();
        #pragma unroll 8
        for (int kk = 0; kk < KT; ++kk) {
            const float a0 = As[kk * ET + eS];
            const float a1 = As[kk * ET + eS + 1];
            const float* wr = &W1[kk * 96 + wS];
            #pragma unroll
            for (int q = 0; q < 6; ++q) {
                accS[0][q] += a0 * wr[q];
                accS[1][q] += a1 * wr[q];
            }
        }
        __syncthreads();
    }
    #pragma unroll
    for (int q = 0; q < 6; ++q) {
        ms_sh[eS * 97 + wS + q]       = accS[0][q];
        ms_sh[(eS + 1) * 97 + wS + q] = accS[1][q];
    }
    __syncthreads();

    // ---- vector path: mv[e][w<32][m] = sum_{k<768} Am[e][k] * Wcat2[k][w]
    //      k<512: xs[u]*yv[v][m] ; k>=512: xv[u][m]*ys[v]
    float accV[3][4] = {};
    const int eV = t >> 3;         // micro-tile: 1 edge x 4 outputs x 3 m
    const int wV = 4 * (t & 7);
    for (int kt = 0; kt < 768; kt += KT) {
        for (int idx = t; idx < 3 * KT * ET; idx += 256) {
            const int m  = idx >> 11;
            const int r2 = idx & 2047;
            const int kk = r2 >> 5, e = r2 & 31, k = kt + kk;
            float v;
            if (k < 512) {
                v = nf_sh[e][k >> 3] * ea_sh[e][8 + 3 * (k & 7) + m];
            } else {
                const int r = k - 512;
                v = nf_sh[e][64 + 3 * (r >> 3) + m] * ea_sh[e][r & 7];
            }
            Av[(m * KT + kk) * ET + e] = v;
        }
        for (int idx = t; idx < KT * 32; idx += 256) {
            const int kk = idx >> 5, w = idx & 31, k = kt + kk;
            const float wv = (k < 512) ? Wsv[(size_t)k * 32 + w]
                                       : Wvs[(size_t)(k - 512) * 32 + w];
            W2[kk * 32 + w] = wv * INV_SQRT768;
        }
        __syncthreads();
        #pragma unroll 8
        for (int kk = 0; kk < KT; ++kk) {
            const float* wr = &W2[kk * 32 + wV];
            const float b0 = wr[0], b1 = wr[1], b2 = wr[2], b3 = wr[3];
            #pragma unroll
            for (int m = 0; m < 3; ++m) {
                const float a = Av[(m * KT + kk) * ET + eV];
                accV[m][0] += a * b0; accV[m][1] += a * b1;
                accV[m][2] += a * b2; accV[m][3] += a * b3;
            }
        }
        __syncthreads();
    }

    // ---- gate: silu on ms[0:64], sigmoid(ms[64:96]) gates vectors
    #pragma unroll
    for (int q = 0; q < 4; ++q) {
        const int w = wV + q;
        const float g = fsigmoid(ms_sh[eV * 97 + 64 + w]);
        #pragma unroll
        for (int m = 0; m < 3; ++m)
            pv_sh[eV * 97 + w * 3 + m] = accV[m][q] * g;
    }
    for (int idx = t; idx < ET * 64; idx += 256) {
        const int e = idx >> 6, u = idx & 63;
        pl_sh[e * 65 + u] = fsilu(ms_sh[e * 97 + u]);
    }
    __syncthreads();

    // ---- linear (Wls: L1-resident 24KB) + fused scatter-sum via atomics
    for (int idx = t; idx < ET * 96; idx += 256) {
        const int e = idx / 96, w = idx - (idx / 96) * 96;
        const float* p = &pl_sh[e * 65];
        float acc = 0.f;
        #pragma unroll 8
        for (int u = 0; u < 64; ++u) acc += p[u] * Wls[u * 96 + w];
        atomicAdd(&agg[(size_t)row_sh[e] * AGG_DIM + w], acc * 0.125f);
    }
    for (int idx = t; idx < ET * 96; idx += 256) {
        const int e = idx / 96, r = idx - (idx / 96) * 96;
        const int w2 = r / 3, m = r - w2 * 3;
        const float* p = &pv_sh[e * 97 + m];
        float acc = 0.f;
        #pragma unroll 8
        for (int u = 0; u < 32; ++u) acc += p[u * 3] * Wlv[u * 32 + w2];
        atomicAdd(&agg[(size_t)row_sh[e] * AGG_DIM + 96 + r], acc * INV_SQRT32);
    }
}

// ============================ update kernel ============================
// 32 nodes/block. FCTP(ns, agg) -> gate -> linear -> residual -> out.
__global__ __launch_bounds__(256, 2) void upd_kernel(
    const float* __restrict__ nf, const float* __restrict__ agg,
    const float* __restrict__ Wss, const float* __restrict__ Wvv,
    const float* __restrict__ Wsv, const float* __restrict__ Wvs,
    const float* __restrict__ Wls, const float* __restrict__ Wlv,
    float* __restrict__ out)
{
    constexpr int NT = 32, KT = 32;
    __shared__ float nf_sh[NT][161];
    __shared__ float ag_sh[NT][193];
    __shared__ float pool[7200];
    float* const us_sh = pool;          // [32][97]
    float* const As    = pool + 3104;   // [32][32]
    float* const W1    = pool + 4128;   // [32][96]
    float* const Av    = pool + 3104;   // [3][32][32]
    float* const W2    = pool + 6176;   // [32][32]
    float* const gv_sh = pool + 3104;   // [32][97]

    const int t = threadIdx.x;
    const int nblk = blockIdx.x * NT;

    {
        const int i = t >> 3, j = t & 7;
        int n = nblk + i; if (n > kNodes - 1) n = kNodes - 1;  // tail clamp
        const float* src = nf + (size_t)n * NF_DIM;
        for (int c = j; c < NF_DIM; c += 8) nf_sh[i][c] = src[c];
        const float* asrc = agg + (size_t)n * AGG_DIM;
        for (int c = j; c < AGG_DIM; c += 8) ag_sh[i][c] = asrc[c];
    }
    __syncthreads();

    // ---- scalar path: K = 64*96 (ns x agg_s) + 32*32 (nv . agg_v) = 7168
    float accS[2][6] = {};
    const int eS = 2 * (t >> 4);
    const int wS = 6 * (t & 15);
    for (int kt = 0; kt < 7168; kt += KT) {
        for (int idx = t; idx < KT * NT; idx += 256) {
            const int kk = idx >> 5, n = idx & 31, k = kt + kk;
            float v;
            if (k < 6144) {
                const int u = k / 96, vv = k - u * 96;
                v = nf_sh[n][u] * ag_sh[n][vv];
            } else {
                const int r = k - 6144;
                const float* xv = &nf_sh[n][64 + 3 * (r >> 5)];
                const float* yv = &ag_sh[n][96 + 3 * (r & 31)];
                v = xv[0] * yv[0] + xv[1] * yv[1] + xv[2] * yv[2];
            }
            As[kk * NT + n] = v;
        }
        for (int idx = t; idx < KT * 96; idx += 256) {
            const int kk = idx / 96, w = idx - kk * 96, k = kt + kk;
            const float wv = (k < 6144) ? Wss[(size_t)k * 96 + w]
                                        : Wvv[(size_t)(k - 6144) * 96 + w] * INV_SQRT3;
            W1[kk * 96 + w] = wv * INV_SQRT7168;
        }
        __syncthreads();
        #pragma unroll 8
        for (int kk = 0; kk < KT; ++kk) {
            const float a0 = As[kk * NT + eS];
            const float a1 = As[kk * NT + eS + 1];
            const float* wr = &W1[kk * 96 + wS];
            #pragma unroll
            for (int q = 0; q < 6; ++q) {
                accS[0][q] += a0 * wr[q];
                accS[1][q] += a1 * wr[q];
            }
        }
        __syncthreads();
    }
    #pragma unroll
    for (int q = 0; q < 6; ++q) {
        us_sh[eS * 97 + wS + q]       = accS[0][q];
        us_sh[(eS + 1) * 97 + wS + q] = accS[1][q];
    }
    __syncthreads();

    // ---- vector path: K = 64*32 (ns x agg_v) + 32*96 (nv x agg_s) = 5120
    float accV[3][4] = {};
    const int eV = t >> 3;
    const int wV = 4 * (t & 7);
    for (int kt = 0; kt < 5120; kt += KT) {
        for (int idx = t; idx < 3 * KT * NT; idx += 256) {
            const int m  = idx >> 10;
            const int r2 = idx & 1023;
            const int kk = r2 >> 5, n = r2 & 31, k = kt + kk;
            float v;
            if (k < 2048) {
                v = nf_sh[n][k >> 5] * ag_sh[n][96 + 3 * (k & 31) + m];
            } else {
                const int r = k - 2048;
                const int u = r / 96, vv = r - u * 96;
                v = nf_sh[n][64 + 3 * u + m] * ag_sh[n][vv];
            }
            Av[(m * KT + kk) * NT + n] = v;
        }
        for (int idx = t; idx < KT * 32; idx += 256) {
            const int kk = idx >> 5, w = idx & 31, k = kt + kk;
            const float wv = (k < 2048) ? Wsv[(size_t)k * 32 + w]
                                        : Wvs[(size_t)(k - 2048) * 32 + w];
            W2[kk * 32 + w] = wv * INV_SQRT5120;
        }
        __syncthreads();
        #pragma unroll 8
        for (int kk = 0; kk < KT; ++kk) {
            const float* wr = &W2[kk * 32 + wV];
            const float b0 = wr[0], b1 = wr[1], b2 = wr[2], b3 = wr[3];
            #pragma unroll
            for (int m = 0; m < 3; ++m) {
                const float a = Av[(m * KT + kk) * NT + eV];
                accV[m][0] += a * b0; accV[m][1] += a * b1;
                accV[m][2] += a * b2; accV[m][3] += a * b3;
            }
        }
        __syncthreads();
    }

    // ---- gate
    #pragma unroll
    for (int q = 0; q < 4; ++q) {
        const int w = wV + q;
        const float g = fsigmoid(us_sh[eV * 97 + 64 + w]);
        #pragma unroll
        for (int m = 0; m < 3; ++m)
            gv_sh[eV * 97 + w * 3 + m] = accV[m][q] * g;
    }
    __syncthreads();
    for (int idx = t; idx < NT * 64; idx += 256) {
        const int n = idx >> 6, u = idx & 63;
        us_sh[n * 97 + u] = fsilu(us_sh[n * 97 + u]);  // gates already consumed
    }
    __syncthreads();

    // ---- linear + residual
    const int nvalid = kNodes - nblk;
    for (int idx = t; idx < NT * 64; idx += 256) {
        const int n = idx >> 6, w = idx & 63;
        if (n < nvalid) {
            const float* p = &us_sh[n * 97];
            float acc = 0.f;
            #pragma unroll 8
            for (int u = 0; u < 64; ++u) acc += p[u] * Wls[u * 64 + w];
            out[(size_t)(nblk + n) * NF_DIM + w] = nf_sh[n][w] + acc * 0.125f;
        }
    }
    for (int idx = t; idx < NT * 96; idx += 256) {
        const int n = idx / 96, r = idx - (idx / 96) * 96;
        if (n < nvalid) {
            const int w2 = r / 3, m = r - w2 * 3;
            const float* p = &gv_sh[n * 97 + m];
            float acc = 0.f;
            #pragma unroll 8
            for (int u = 0; u < 32; ++u) acc += p[u * 3] * Wlv[u * 32 + w2];
            out[(size_t)(nblk + n) * NF_DIM + 64 + r] = nf_sh[n][64 + r] + acc * INV_SQRT32;
        }
    }
}

extern "C" void kernel_launch(void* const* d_in, const int* in_sizes, int n_in,
                              void* d_out, int out_size, void* d_ws, size_t ws_size,
                              hipStream_t stream) {
    const float* nf   = (const float*)d_in[0];
    const float* ea   = (const float*)d_in[1];
    const float* Wmss = (const float*)d_in[2];
    const float* Wmvv = (const float*)d_in[3];
    const float* Wmsv = (const float*)d_in[4];
    const float* Wmvs = (const float*)d_in[5];
    const float* Wlms = (const float*)d_in[6];
    const float* Wlmv = (const float*)d_in[7];
    const float* Wuss = (const float*)d_in[8];
    const float* Wuvv = (const float*)d_in[9];
    const float* Wusv = (const float*)d_in[10];
    const float* Wuvs = (const float*)d_in[11];
    const float* Wlus = (const float*)d_in[12];
    const float* Wluv = (const float*)d_in[13];
    const int*   eidx = (const int*)d_in[14];
    float* agg = (float*)d_ws;                       // [10000][192] accumulator
    float* out = (float*)d_out;

    hipMemsetAsync(agg, 0, (size_t)kNodes * AGG_DIM * sizeof(float), stream);
    msg_kernel<<<kEdges / 32, 256, 0, stream>>>(nf, ea, Wmss, Wmvv, Wmsv, Wmvs,
                                                Wlms, Wlmv, eidx, agg);
    upd_kernel<<<(kNodes + 31) / 32, 256, 0, stream>>>(nf, agg, Wuss, Wuvv, Wusv,
                                                       Wuvs, Wlus, Wluv, out);
}

// Round 3
// 637.457 us; speedup vs baseline: 5.2565x; 5.2565x over previous
//
#include <hip/hip_runtime.h>

// irreps: node = 64x0e + 32x1o (160 f32), edge = 8x0e + 8x1o (32 f32)
// hidden = 96x0e + 32x1o ; agg row = 96 scalars + 32*3 vectors = 192 f32
constexpr int kNodes = 10000;
constexpr int kEdges = 100000;

constexpr float INV_SQRT3    = 0.57735026918962576f;
constexpr float INV_SQRT768  = 0.036084391824351615f;  // msg fan
constexpr float INV_SQRT7168 = 0.011811389781538352f;  // upd scalar fan
constexpr float INV_SQRT5120 = 0.013975424859373686f;  // upd vector fan
constexpr float INV_SQRT32   = 0.17677669529663687f;

// d_ws: ONLY the f32 agg accumulator [10000][192] = 7,680,000 B (proven safe size).
// Prepped bf16 weights live in d_out (6.4 MB) until the final copy overwrites it:
constexpr size_t MSGW_OFF  = 0;           // 24 tiles x 10240B ([96+32][40] bf16)
constexpr size_t UPDW1_OFF = 245760;      // 224 tiles x 8192B ([96][40] + pad)
constexpr size_t UPDW2_OFF = 2080768;     // 160 tiles x 3072B ([32][40] + pad)
constexpr size_t MLIN_OFF  = 2572288;     // 16384B: WlsT[96][72] + WlvT[32][40]
constexpr size_t ULIN_OFF  = 2588672;     // 12288B: WlsT[64][72] + WlvT[32][40]
// total 2,600,960 B < 6,400,000 B (d_out)

typedef __attribute__((ext_vector_type(8))) short bf8;  // 8 bf16 (4 VGPR) MFMA operand
typedef __attribute__((ext_vector_type(4))) float f4;   // MFMA accumulator
union BF { bf8 v; short s[8]; };

__device__ __forceinline__ short f2bf(float f) {   // RNE f32->bf16
    union { float f; unsigned u; } c; c.f = f;
    unsigned r = c.u + 0x7fffu + ((c.u >> 16) & 1u);
    return (short)(r >> 16);
}
__device__ __forceinline__ f4 mfma16(bf8 a, bf8 b, f4 c) {
    return __builtin_amdgcn_mfma_f32_16x16x32_bf16(a, b, c, 0, 0, 0);
}
__device__ __forceinline__ void gl2lds(const void* g, void* l) {  // 16B/lane async copy
    __builtin_amdgcn_global_load_lds(
        (const __attribute__((address_space(1))) unsigned int*)g,
        (__attribute__((address_space(3))) unsigned int*)l, 16, 0, 0);
}
__device__ __forceinline__ float fsig(float x) { return 1.0f / (1.0f + __expf(-x)); }

// ================= prep: scale + transpose + reorder weights to bf16 (into d_out) ==========
__global__ void prep_kernel(
    const float* __restrict__ Wmss, const float* __restrict__ Wmvv,
    const float* __restrict__ Wmsv, const float* __restrict__ Wmvs,
    const float* __restrict__ Wlms, const float* __restrict__ Wlmv,
    const float* __restrict__ Wuss, const float* __restrict__ Wuvv,
    const float* __restrict__ Wusv, const float* __restrict__ Wuvs,
    const float* __restrict__ Wlus, const float* __restrict__ Wluv,
    char* __restrict__ wout)
{
    int i = blockIdx.x * 256 + threadIdx.x;
    float v = 0.f;
    short* dst;
    if (i < 122880) {                       // msgW: [24][128 rows][40]
        dst = (short*)(wout + MSGW_OFF) + i;
        int t = i / 5120, q = i % 5120, r = q / 40, c = q % 40;
        if (c < 32) {
            int k = t * 32 + c;
            if (r < 96) {                   // W1: scalar out. k<512: ss (k=u*8+v). else vv (nat)
                v = (k < 512 ? Wmss[k * 96 + r]
                             : Wmvv[(k - 512) * 96 + r] * INV_SQRT3) * INV_SQRT768;
            } else {                        // W2: vector out. k<512: sv REORDERED k=v*64+u. else vs nat
                int n2 = r - 96;
                if (k < 512) { int u = k & 63, vv = k >> 6; v = Wmsv[(u * 8 + vv) * 32 + n2] * INV_SQRT768; }
                else         { v = Wmvs[(k - 512) * 32 + n2] * INV_SQRT768; }
            }
        }
    } else if (i < 1040384) {               // updW1: [224][96][40] (+pad to 4096 elems/tile)
        int j = i - 122880;
        dst = (short*)(wout + UPDW1_OFF) + j;
        int t = j / 4096, q = j % 4096, r = q / 40, c = q % 40;
        if (q < 3840 && c < 32) {
            int k = t * 32 + c;
            if (k < 6144) { int u = k & 63, vv = k >> 6;          // ss REORDERED k=v*64+u
                v = Wuss[(u * 96 + vv) * 96 + r] * INV_SQRT7168; }
            else { int r2 = k - 6144; int u = r2 & 31, vv = r2 >> 5;  // vv REORDERED k=v*32+u
                v = Wuvv[(u * 32 + vv) * 96 + r] * (INV_SQRT3 * INV_SQRT7168); }
        }
    } else if (i < 1286144) {               // updW2: [160][32][40] (+pad to 1536)
        int j = i - 1040384;
        dst = (short*)(wout + UPDW2_OFF) + j;
        int t = j / 1536, q = j % 1536, r = q / 40, c = q % 40;
        if (q < 1280 && c < 32) {
            int k = t * 32 + c;
            if (k < 2048) { int u = k & 63, vv = k >> 6;          // sv REORDERED k=v*64+u
                v = Wusv[(u * 32 + vv) * 32 + r] * INV_SQRT5120; }
            else { int r2 = k - 2048;                              // vs natural u*96+v
                v = Wuvs[r2 * 32 + r] * INV_SQRT5120; }
        }
    } else if (i < 1294336) {               // mLin: WlsT [96][72] then WlvT [32][40]
        int j = i - 1286144;
        dst = (short*)(wout + MLIN_OFF) + j;
        if (j < 6912) { int n = j / 72, kk = j % 72; if (kk < 64) v = Wlms[kk * 96 + n] * 0.125f; }
        else { int j2 = j - 6912; int n = j2 / 40, kk = j2 % 40; if (kk < 32) v = Wlmv[kk * 32 + n] * INV_SQRT32; }
    } else if (i < 1300480) {               // uLin: WlsT [64][72] then WlvT [32][40]
        int j = i - 1294336;
        dst = (short*)(wout + ULIN_OFF) + j;
        if (j < 4608) { int n = j / 72, kk = j % 72; if (kk < 64) v = Wlus[kk * 64 + n] * 0.125f; }
        else if (j < 5888) { int j2 = j - 4608; int n = j2 / 40, kk = j2 % 40; if (kk < 32) v = Wluv[kk * 32 + n] * INV_SQRT32; }
        else v = 0.f;
    } else return;
    *dst = f2bf(v);
}

// ================= message kernel: 32 edges/block, 4 waves, MFMA =================
__global__ __launch_bounds__(256, 2) void msg_kernel(
    const float* __restrict__ nf, const float* __restrict__ ea,
    const int* __restrict__ eidx, const char* __restrict__ wout,
    float* __restrict__ agg)
{
    __shared__ char pool[79488];
    float* nf_sh  = (float*)pool;                  // [32][164] f32
    float* ea_sh  = (float*)(pool + 20992);        // [32][36]
    int*   row_sh = (int*)  (pool + 25600);        // [32]
    short* wbuf   = (short*)(pool + 25728);        // [2][5120]: W1t[96][40] + W2t[32][40]
    short* lin    = (short*)(pool + 46208);        // [8192]: WlsT[96][72], WlvT @6912
    float* gat    = (float*)(pool + 62592);        // [32][36]
    short* silu_s = (short*)(pool + 67200);        // [32][72] bf16
    short* pv_s   = (short*)(pool + 71808);        // [96][40] bf16  (rows = m*32+e)

    const int t = threadIdx.x, w = t >> 6, lane = t & 63;
    const int l15 = lane & 15, lg = lane >> 4;     // lg in [0,4): k-group
    const int eblk = blockIdx.x * 32;

    const char* msgW = wout + MSGW_OFF;
    const char* mlin = wout + MLIN_OFF;

    // issue epilogue-linear weights (16KB) + K-tile 0 (10KB) async
    for (int c = w; c < 16; c += 4) gl2lds(mlin + c * 1024 + lane * 16, (char*)lin + c * 1024);
    for (int c = w; c < 10; c += 4) gl2lds(msgW + c * 1024 + lane * 16, (char*)wbuf + c * 1024);

    {   // stage gathered src-node rows + edge attrs (f32)
        const int i = t >> 3, j = t & 7;
        const int e = eblk + i;
        if (j == 0) row_sh[i] = eidx[e];
        const int col = eidx[kEdges + e];
        const float4* src = (const float4*)(nf + (size_t)col * 160);
        for (int c = j; c < 40; c += 8) *(float4*)&nf_sh[i * 164 + c * 4] = src[c];
        const float4* esrc = (const float4*)(ea + (size_t)e * 32);
        *(float4*)&ea_sh[i * 36 + j * 4] = esrc[j];
    }
    __syncthreads();

    // ---- main K-loop: 24 tiles of K=32. scalar GEMM [32,768]@[768,96],
    //      vector GEMM [96(m,e),768]@[768,32]. per wave: 3 scalar + 3 vector C-tiles.
    f4 accS[3] = {{0.f,0.f,0.f,0.f},{0.f,0.f,0.f,0.f},{0.f,0.f,0.f,0.f}};
    f4 accV[3] = {{0.f,0.f,0.f,0.f},{0.f,0.f,0.f,0.f},{0.f,0.f,0.f,0.f}};
    const int Ms = w >> 1, nb = (w & 1) * 3;       // scalar M-tile, n-tile base
    const int es_ = Ms * 16 + l15;                 // scalar A row (edge)

    for (int kt = 0; kt < 24; ++kt) {
        const short* wb = wbuf + (kt & 1) * 5120;
        if (kt + 1 < 24)                            // prefetch next K-tile
            for (int c = w; c < 10; c += 4)
                gl2lds(msgW + (kt + 1) * 10240 + c * 1024 + lane * 16,
                       (char*)(wbuf + ((kt + 1) & 1) * 5120) + c * 1024);

        // scalar A-frag: k = kt*32 + lg*8 + j
        BF aS;
        if (kt < 16) {                              // ss: A[j] = xs[u] * ys[j]
            const int uu = kt * 4 + lg;
            const float xs = nf_sh[es_ * 164 + uu];
            const float4 y0 = *(const float4*)&ea_sh[es_ * 36];
            const float4 y1 = *(const float4*)&ea_sh[es_ * 36 + 4];
            aS.s[0]=f2bf(xs*y0.x); aS.s[1]=f2bf(xs*y0.y); aS.s[2]=f2bf(xs*y0.z); aS.s[3]=f2bf(xs*y0.w);
            aS.s[4]=f2bf(xs*y1.x); aS.s[5]=f2bf(xs*y1.y); aS.s[6]=f2bf(xs*y1.z); aS.s[7]=f2bf(xs*y1.w);
        } else {                                    // vv: A[j] = dot(xv[u], yv[j]) (w3j folded in W)
            const int uu = (kt - 16) * 4 + lg;
            const float* xp = &nf_sh[es_ * 164 + 64 + 3 * uu];
            const float x0 = xp[0], x1 = xp[1], x2 = xp[2];
            const float* yp = &ea_sh[es_ * 36 + 8];
            #pragma unroll
            for (int j = 0; j < 8; ++j)
                aS.s[j] = f2bf(x0 * yp[3*j] + x1 * yp[3*j+1] + x2 * yp[3*j+2]);
        }
        #pragma unroll
        for (int i = 0; i < 3; ++i) {
            bf8 b = *(const bf8*)&wb[((nb + i) * 16 + l15) * 40 + lg * 8];
            accS[i] = mfma16(aS.v, b, accS[i]);
        }

        // vector tiles: tv = 3w+i -> Mv = tv>>1 (row-tile: m = Mv>>1, e-half = Mv&1), Nv = tv&1
        BF aV; int prevMv = -1;
        #pragma unroll
        for (int i = 0; i < 3; ++i) {
            const int tv = 3 * w + i, Mv = tv >> 1, Nv = tv & 1;
            if (Mv != prevMv) {
                prevMv = Mv;
                const int m = Mv >> 1, ev = (Mv & 1) * 16 + l15;
                if (kt < 16) {                      // sv (k reordered v*64+u): A[j] = xs[u0+j]*yv[v][m]
                    const int kp = kt * 32 + lg * 8;
                    const int vv = kp >> 6, u0 = kp & 63;
                    const float ym = ea_sh[ev * 36 + 8 + 3 * vv + m];
                    const float4 x0 = *(const float4*)&nf_sh[ev * 164 + u0];
                    const float4 x1 = *(const float4*)&nf_sh[ev * 164 + u0 + 4];
                    aV.s[0]=f2bf(x0.x*ym); aV.s[1]=f2bf(x0.y*ym); aV.s[2]=f2bf(x0.z*ym); aV.s[3]=f2bf(x0.w*ym);
                    aV.s[4]=f2bf(x1.x*ym); aV.s[5]=f2bf(x1.y*ym); aV.s[6]=f2bf(x1.z*ym); aV.s[7]=f2bf(x1.w*ym);
                } else {                            // vs (natural u*8+v): A[j] = xv[u][m]*ys[j]
                    const int uu = (kt - 16) * 4 + lg;
                    const float xm = nf_sh[ev * 164 + 64 + 3 * uu + m];
                    const float4 y0 = *(const float4*)&ea_sh[ev * 36];
                    const float4 y1 = *(const float4*)&ea_sh[ev * 36 + 4];
                    aV.s[0]=f2bf(xm*y0.x); aV.s[1]=f2bf(xm*y0.y); aV.s[2]=f2bf(xm*y0.z); aV.s[3]=f2bf(xm*y0.w);
                    aV.s[4]=f2bf(xm*y1.x); aV.s[5]=f2bf(xm*y1.y); aV.s[6]=f2bf(xm*y1.z); aV.s[7]=f2bf(xm*y1.w);
                }
            }
            bf8 b = *(const bf8*)&wb[3840 + (Nv * 16 + l15) * 40 + lg * 8];
            accV[i] = mfma16(aV.v, b, accV[i]);
        }
        __syncthreads();
    }

    // ---- epilogue: silu/gates from scalar C (rows e = Ms*16 + lg*4 + r, col n)
    #pragma unroll
    for (int i = 0; i < 3; ++i) {
        const int n = (nb + i) * 16 + l15;
        #pragma unroll
        for (int r = 0; r < 4; ++r) {
            const int e = Ms * 16 + lg * 4 + r;
            const float v = accS[i][r];
            if (n < 64) silu_s[e * 72 + n] = f2bf(v * fsig(v));
            else        gat[e * 36 + (n - 64)] = fsig(v);
        }
    }
    __syncthreads();
    // gate vectors -> pv (bf16)
    #pragma unroll
    for (int i = 0; i < 3; ++i) {
        const int tv = 3 * w + i, Mv = tv >> 1, Nv = tv & 1;
        const int m = Mv >> 1, eb = (Mv & 1) * 16;
        const int u = Nv * 16 + l15;
        #pragma unroll
        for (int r = 0; r < 4; ++r) {
            const int e = eb + lg * 4 + r;
            pv_s[(m * 32 + e) * 40 + u] = f2bf(accV[i][r] * gat[e * 36 + u]);
        }
    }
    __syncthreads();

    // ---- linear (MFMA) + fused atomic scatter. scales folded into weights.
    {   // ls: [32,64] @ WlsT -> [32,96]
        f4 acc[3] = {{0.f,0.f,0.f,0.f},{0.f,0.f,0.f,0.f},{0.f,0.f,0.f,0.f}};
        #pragma unroll
        for (int k0 = 0; k0 < 2; ++k0) {
            const int kg = k0 * 32 + lg * 8;
            bf8 a = *(const bf8*)&silu_s[es_ * 72 + kg];
            #pragma unroll
            for (int i = 0; i < 3; ++i) {
                bf8 b = *(const bf8*)&lin[((nb + i) * 16 + l15) * 72 + kg];
                acc[i] = mfma16(a, b, acc[i]);
            }
        }
        #pragma unroll
        for (int i = 0; i < 3; ++i) {
            const int n = (nb + i) * 16 + l15;
            #pragma unroll
            for (int r = 0; r < 4; ++r) {
                const int e = Ms * 16 + lg * 4 + r;
                atomicAdd(&agg[(size_t)row_sh[e] * 192 + n], acc[i][r]);
            }
        }
    }
    {   // lv: [96,32] @ WlvT -> [96,32]; rows rr -> (m = rr>>5, e = rr&31)
        f4 acc[3] = {{0.f,0.f,0.f,0.f},{0.f,0.f,0.f,0.f},{0.f,0.f,0.f,0.f}};
        const int kg = lg * 8;
        BF a; int prevMv = -1;
        #pragma unroll
        for (int i = 0; i < 3; ++i) {
            const int tv = 3 * w + i, Mv = tv >> 1, Nv = tv & 1;
            if (Mv != prevMv) { prevMv = Mv; a.v = *(const bf8*)&pv_s[(Mv * 16 + l15) * 40 + kg]; }
            bf8 b = *(const bf8*)&lin[6912 + (Nv * 16 + l15) * 40 + kg];
            acc[i] = mfma16(a.v, b, acc[i]);
        }
        #pragma unroll
        for (int i = 0; i < 3; ++i) {
            const int tv = 3 * w + i, Mv = tv >> 1, Nv = tv & 1;
            const int w2 = Nv * 16 + l15;
            #pragma unroll
            for (int r = 0; r < 4; ++r) {
                const int rr = Mv * 16 + lg * 4 + r;
                const int m = rr >> 5, e = rr & 31;
                atomicAdd(&agg[(size_t)row_sh[e] * 192 + 96 + w2 * 3 + m], acc[i][r]);
            }
        }
    }
}

// ================= update kernel: 32 nodes/block, 4 waves, MFMA =================
// Result (residual+delta) is written into agg rows (cols 0..159) — block-private.
__global__ __launch_bounds__(256, 1) void upd_kernel(
    const float* __restrict__ nf, const char* __restrict__ wout,
    float* __restrict__ agg)
{
    __shared__ char pool[140800];
    float* nf_sh  = (float*)pool;                  // [32][164]
    float* ag_sh  = (float*)(pool + 20992);        // [32][196]
    short* wbuf   = (short*)(pool + 46080);        // [2][16384]: 4 K-tiles per stage
    short* lin    = (short*)(pool + 111616);       // [6144]: WlsT[64][72], WlvT @4608
    float* gat    = (float*)(pool + 123904);       // [32][36]
    short* silu_s = (short*)(pool + 128512);       // [32][72]
    short* gv_s   = (short*)(pool + 133120);       // [96][40]

    const int t = threadIdx.x, w = t >> 6, lane = t & 63;
    const int l15 = lane & 15, lg = lane >> 4;
    const int nblk = blockIdx.x * 32;
    const char* W1 = wout + UPDW1_OFF;
    const char* W2 = wout + UPDW2_OFF;

    for (int c = w; c < 12; c += 4) gl2lds(wout + ULIN_OFF + c * 1024 + lane * 16, (char*)lin + c * 1024);
    for (int c = w; c < 32; c += 4) gl2lds(W1 + c * 1024 + lane * 16, (char*)wbuf + c * 1024);

    {   // stage node rows + agg rows (clamp tail)
        const int i = t >> 3, j = t & 7;
        int n = nblk + i; if (n > kNodes - 1) n = kNodes - 1;
        const float4* src = (const float4*)(nf + (size_t)n * 160);
        for (int c = j; c < 40; c += 8) *(float4*)&nf_sh[i * 164 + c * 4] = src[c];
        const float4* asrc = (const float4*)(agg + (size_t)n * 192);
        for (int c = j; c < 48; c += 8) *(float4*)&ag_sh[i * 196 + c * 4] = asrc[c];
    }
    __syncthreads();

    const int Ms = w >> 1, nb = (w & 1) * 3;
    const int es_ = Ms * 16 + l15;

    // ---- scalar K-loop: 224 tiles (56 stages of 4). K<6144: ss (v*64+u); else vv (v*32+u)
    f4 accS[3] = {{0.f,0.f,0.f,0.f},{0.f,0.f,0.f,0.f},{0.f,0.f,0.f,0.f}};
    for (int s = 0; s < 56; ++s) {
        if (s + 1 < 56)
            for (int c = w; c < 32; c += 4)
                gl2lds(W1 + (size_t)(s + 1) * 32768 + c * 1024 + lane * 16,
                       (char*)(wbuf + ((s + 1) & 1) * 16384) + c * 1024);
        #pragma unroll
        for (int tl = 0; tl < 4; ++tl) {
            const int kt = s * 4 + tl;
            const short* wb = wbuf + (s & 1) * 16384 + tl * 4096;
            BF aS;
            if (kt < 192) {                          // A[j] = ns[u0+j] * agg_s[v]
                const int kp = kt * 32 + lg * 8;
                const int vv = kp >> 6, u0 = kp & 63;
                const float ys = ag_sh[es_ * 196 + vv];
                const float4 x0 = *(const float4*)&nf_sh[es_ * 164 + u0];
                const float4 x1 = *(const float4*)&nf_sh[es_ * 164 + u0 + 4];
                aS.s[0]=f2bf(x0.x*ys); aS.s[1]=f2bf(x0.y*ys); aS.s[2]=f2bf(x0.z*ys); aS.s[3]=f2bf(x0.w*ys);
                aS.s[4]=f2bf(x1.x*ys); aS.s[5]=f2bf(x1.y*ys); aS.s[6]=f2bf(x1.z*ys); aS.s[7]=f2bf(x1.w*ys);
            } else {                                 // A[j] = dot(nv[u0+j], agg_v[v])
                const int rp = kt * 32 + lg * 8 - 6144;
                const int vv = rp >> 5, u0 = rp & 31;
                const float* xp = &nf_sh[es_ * 164 + 64 + 3 * u0];
                const float* gp = &ag_sh[es_ * 196 + 96 + 3 * vv];
                const float g0 = gp[0], g1 = gp[1], g2 = gp[2];
                #pragma unroll
                for (int j = 0; j < 8; ++j)
                    aS.s[j] = f2bf(xp[3*j] * g0 + xp[3*j+1] * g1 + xp[3*j+2] * g2);
            }
            #pragma unroll
            for (int i = 0; i < 3; ++i) {
                bf8 b = *(const bf8*)&wb[((nb + i) * 16 + l15) * 40 + lg * 8];
                accS[i] = mfma16(aS.v, b, accS[i]);
            }
        }
        __syncthreads();
    }

    // scalar epilogue -> silu/gates
    #pragma unroll
    for (int i = 0; i < 3; ++i) {
        const int n = (nb + i) * 16 + l15;
        #pragma unroll
        for (int r = 0; r < 4; ++r) {
            const int e = Ms * 16 + lg * 4 + r;
            const float v = accS[i][r];
            if (n < 64) silu_s[e * 72 + n] = f2bf(v * fsig(v));
            else        gat[e * 36 + (n - 64)] = fsig(v);
        }
    }
    // issue vector stage 0
    for (int c = w; c < 12; c += 4) gl2lds(W2 + c * 1024 + lane * 16, (char*)wbuf + c * 1024);
    __syncthreads();

    // ---- vector K-loop: 160 tiles (40 stages of 4). K<2048: sv (v*64+u); else vs (u*96+v)
    f4 accV[3] = {{0.f,0.f,0.f,0.f},{0.f,0.f,0.f,0.f},{0.f,0.f,0.f,0.f}};
    for (int s = 0; s < 40; ++s) {
        if (s + 1 < 40)
            for (int c = w; c < 12; c += 4)
                gl2lds(W2 + (size_t)(s + 1) * 12288 + c * 1024 + lane * 16,
                       (char*)(wbuf + ((s + 1) & 1) * 16384) + c * 1024);
        #pragma unroll
        for (int tl = 0; tl < 4; ++tl) {
            const int kt = s * 4 + tl;
            const short* wb = wbuf + (s & 1) * 16384 + tl * 1536;
            BF aV; int prevMv = -1;
            #pragma unroll
            for (int i = 0; i < 3; ++i) {
                const int tv = 3 * w + i, Mv = tv >> 1, Nv = tv & 1;
                if (Mv != prevMv) {
                    prevMv = Mv;
                    const int m = Mv >> 1, ev = (Mv & 1) * 16 + l15;
                    if (kt < 64) {                   // A[j] = ns[u0+j] * agg_v[v][m]
                        const int kp = kt * 32 + lg * 8;
                        const int vv = kp >> 6, u0 = kp & 63;
                        const float ym = ag_sh[ev * 196 + 96 + 3 * vv + m];
                        const float4 x0 = *(const float4*)&nf_sh[ev * 164 + u0];
                        const float4 x1 = *(const float4*)&nf_sh[ev * 164 + u0 + 4];
                        aV.s[0]=f2bf(x0.x*ym); aV.s[1]=f2bf(x0.y*ym); aV.s[2]=f2bf(x0.z*ym); aV.s[3]=f2bf(x0.w*ym);
                        aV.s[4]=f2bf(x1.x*ym); aV.s[5]=f2bf(x1.y*ym); aV.s[6]=f2bf(x1.z*ym); aV.s[7]=f2bf(x1.w*ym);
                    } else {                         // A[j] = nv[u][m] * agg_s[v0+j]
                        const int rp = kt * 32 + lg * 8 - 2048;
                        const int u = rp / 96, v0 = rp - u * 96;
                        const float xm = nf_sh[ev * 164 + 64 + 3 * u + m];
                        const float4 y0 = *(const float4*)&ag_sh[ev * 196 + v0];
                        const float4 y1 = *(const float4*)&ag_sh[ev * 196 + v0 + 4];
                        aV.s[0]=f2bf(xm*y0.x); aV.s[1]=f2bf(xm*y0.y); aV.s[2]=f2bf(xm*y0.z); aV.s[3]=f2bf(xm*y0.w);
                        aV.s[4]=f2bf(xm*y1.x); aV.s[5]=f2bf(xm*y1.y); aV.s[6]=f2bf(xm*y1.z); aV.s[7]=f2bf(xm*y1.w);
                    }
                }
                bf8 b = *(const bf8*)&wb[(Nv * 16 + l15) * 40 + lg * 8];
                accV[i] = mfma16(aV.v, b, accV[i]);
            }
        }
        __syncthreads();
    }

    // gate vectors -> gv
    #pragma unroll
    for (int i = 0; i < 3; ++i) {
        const int tv = 3 * w + i, Mv = tv >> 1, Nv = tv & 1;
        const int m = Mv >> 1, eb = (Mv & 1) * 16;
        const int u = Nv * 16 + l15;
        #pragma unroll
        for (int r = 0; r < 4; ++r) {
            const int e = eb + lg * 4 + r;
            gv_s[(m * 32 + e) * 40 + u] = f2bf(accV[i][r] * gat[e * 36 + u]);
        }
    }
    __syncthreads();

    // ---- final linears (MFMA) + residual -> agg rows (cols 0..159)
    const int nvalid = kNodes - nblk;
    {   // ds: [32,64] @ WlsT_u -> [32,64]; 2M x 4N tiles, 2 per wave
        f4 acc[2] = {{0.f,0.f,0.f,0.f},{0.f,0.f,0.f,0.f}};
        const int nb2 = (w & 1) * 2;
        #pragma unroll
        for (int k0 = 0; k0 < 2; ++k0) {
            const int kg = k0 * 32 + lg * 8;
            bf8 a = *(const bf8*)&silu_s[es_ * 72 + kg];
            #pragma unroll
            for (int i = 0; i < 2; ++i) {
                bf8 b = *(const bf8*)&lin[((nb2 + i) * 16 + l15) * 72 + kg];
                acc[i] = mfma16(a, b, acc[i]);
            }
        }
        #pragma unroll
        for (int i = 0; i < 2; ++i) {
            const int n = (nb2 + i) * 16 + l15;
            #pragma unroll
            for (int r = 0; r < 4; ++r) {
                const int e = Ms * 16 + lg * 4 + r;
                if (e < nvalid)
                    agg[(size_t)(nblk + e) * 192 + n] = nf_sh[e * 164 + n] + acc[i][r];
            }
        }
    }
    {   // dv: [96,32] @ WlvT_u -> [96,32]
        f4 acc[3] = {{0.f,0.f,0.f,0.f},{0.f,0.f,0.f,0.f},{0.f,0.f,0.f,0.f}};
        const int kg = lg * 8;
        BF a; int prevMv = -1;
        #pragma unroll
        for (int i = 0; i < 3; ++i) {
            const int tv = 3 * w + i, Mv = tv >> 1, Nv = tv & 1;
            if (Mv != prevMv) { prevMv = Mv; a.v = *(const bf8*)&gv_s[(Mv * 16 + l15) * 40 + kg]; }
            bf8 b = *(const bf8*)&lin[4608 + (Nv * 16 + l15) * 40 + kg];
            acc[i] = mfma16(a.v, b, acc[i]);
        }
        #pragma unroll
        for (int i = 0; i < 3; ++i) {
            const int tv = 3 * w + i, Mv = tv >> 1, Nv = tv & 1;
            const int w2 = Nv * 16 + l15;
            #pragma unroll
            for (int r = 0; r < 4; ++r) {
                const int rr = Mv * 16 + lg * 4 + r;
                const int m = rr >> 5, e = rr & 31;
                if (e < nvalid)
                    agg[(size_t)(nblk + e) * 192 + 64 + w2 * 3 + m]
                        = nf_sh[e * 164 + 64 + w2 * 3 + m] + acc[i][r];
            }
        }
    }
}

// ================= final copy: agg rows (cols 0..159) -> d_out [10000][160] ==========
__global__ __launch_bounds__(256) void copy_kernel(const float* __restrict__ agg,
                                                   float* __restrict__ out)
{
    int i = blockIdx.x * 256 + threadIdx.x;       // i indexes [10000][40] float4s
    if (i < 400000) {
        int n = i / 40, c = i - n * 40;
        ((float4*)out)[i] = ((const float4*)agg)[n * 48 + c];
    }
}

extern "C" void kernel_launch(void* const* d_in, const int* in_sizes, int n_in,
                              void* d_out, int out_size, void* d_ws, size_t ws_size,
                              hipStream_t stream) {
    const float* nf   = (const float*)d_in[0];
    const float* ea   = (const float*)d_in[1];
    const int*   eidx = (const int*)d_in[14];
    float* agg = (float*)d_ws;                     // f32 [10000][192] — ONLY ws use
    char*  wout = (char*)d_out;                    // weights live here until final copy

    hipMemsetAsync(agg, 0, 7680000, stream);
    prep_kernel<<<5080, 256, 0, stream>>>(
        (const float*)d_in[2], (const float*)d_in[3], (const float*)d_in[4],
        (const float*)d_in[5], (const float*)d_in[6], (const float*)d_in[7],
        (const float*)d_in[8], (const float*)d_in[9], (const float*)d_in[10],
        (const float*)d_in[11], (const float*)d_in[12], (const float*)d_in[13], wout);
    msg_kernel<<<kEdges / 32, 256, 0, stream>>>(nf, ea, eidx, wout, agg);
    upd_kernel<<<(kNodes + 31) / 32, 256, 0, stream>>>(nf, wout, agg);
    copy_kernel<<<1563, 256, 0, stream>>>(agg, (float*)d_out);
}

// Round 6
// 524.289 us; speedup vs baseline: 6.3911x; 1.2158x over previous
//
#include <hip/hip_runtime.h>
#include <hip/hip_bf16.h>

// irreps: node = 64x0e + 32x1o (160 f32), edge = 8x0e + 8x1o (32 f32)
// hidden = 96x0e + 32x1o ; agg row = 96 scalars + 32*3 vectors = 192 f32
constexpr int kNodes = 10000;
constexpr int kEdges = 100000;

constexpr float INV_SQRT3    = 0.57735026918962576f;
constexpr float INV_SQRT768  = 0.036084391824351615f;  // msg fan
constexpr float INV_SQRT7168 = 0.011811389781538352f;  // upd scalar fan
constexpr float INV_SQRT5120 = 0.013975424859373686f;  // upd vector fan
constexpr float INV_SQRT32   = 0.17677669529663687f;

// d_ws: ONLY the f32 agg accumulator [10000][192] = 7,680,000 B (proven safe size).
// Prepped bf16 weights live in d_out (6.4 MB) until the final copy overwrites it:
constexpr size_t MSGW_OFF  = 0;           // 24 tiles x 10240B ([96+32][40] bf16)
constexpr size_t UPDW1_OFF = 245760;      // 224 tiles x 8192B ([96][40] + pad)
constexpr size_t UPDW2_OFF = 2080768;     // 160 tiles x 3072B ([32][40] + pad)
constexpr size_t MLIN_OFF  = 2572288;     // 16384B: WlsT[96][72] + WlvT[32][40]
constexpr size_t ULIN_OFF  = 2588672;     // 12288B: WlsT[64][72] + WlvT[32][40]
// total 2,600,960 B < 6,400,000 B (d_out)

typedef __attribute__((ext_vector_type(8))) short bf8;  // 8 bf16 (4 VGPR) MFMA operand
typedef __attribute__((ext_vector_type(4))) float f4;   // MFMA accumulator
union BF { bf8 v; short s[8]; unsigned u[4]; };

__device__ __forceinline__ short f2bf(float f) {   // RNE f32->bf16 (cold paths)
    union { float f; unsigned u; } c; c.f = f;
    unsigned r = c.u + 0x7fffu + ((c.u >> 16) & 1u);
    return (short)(r >> 16);
}
__device__ __forceinline__ unsigned pk2(float lo, float hi) {  // v_cvt_pk_bf16_f32 (hot paths)
    union { __hip_bfloat162 h; unsigned u; } c;
    c.h = __float22bfloat162_rn(make_float2(lo, hi));
    return c.u;
}
__device__ __forceinline__ f4 mfma16(bf8 a, bf8 b, f4 c) {
    return __builtin_amdgcn_mfma_f32_16x16x32_bf16(a, b, c, 0, 0, 0);
}
__device__ __forceinline__ void gl2lds(const void* g, void* l) {  // 16B/lane async copy
    __builtin_amdgcn_global_load_lds(
        (const __attribute__((address_space(1))) unsigned int*)g,
        (__attribute__((address_space(3))) unsigned int*)l, 16, 0, 0);
}
__device__ __forceinline__ float fsig(float x) { return 1.0f / (1.0f + __expf(-x)); }

// ================= prep: scale + transpose + reorder weights to bf16 (into d_out) ==========
__global__ void prep_kernel(
    const float* __restrict__ Wmss, const float* __restrict__ Wmvv,
    const float* __restrict__ Wmsv, const float* __restrict__ Wmvs,
    const float* __restrict__ Wlms, const float* __restrict__ Wlmv,
    const float* __restrict__ Wuss, const float* __restrict__ Wuvv,
    const float* __restrict__ Wusv, const float* __restrict__ Wuvs,
    const float* __restrict__ Wlus, const float* __restrict__ Wluv,
    char* __restrict__ wout)
{
    int i = blockIdx.x * 256 + threadIdx.x;
    float v = 0.f;
    short* dst;
    if (i < 122880) {                       // msgW: [24][128 rows][40]
        dst = (short*)(wout + MSGW_OFF) + i;
        int t = i / 5120, q = i % 5120, r = q / 40, c = q % 40;
        if (c < 32) {
            int k = t * 32 + c;
            if (r < 96) {                   // W1: scalar out. k<512: ss (k=u*8+v). else vv (nat)
                v = (k < 512 ? Wmss[k * 96 + r]
                             : Wmvv[(k - 512) * 96 + r] * INV_SQRT3) * INV_SQRT768;
            } else {                        // W2: vector out. k<512: sv REORDERED k=v*64+u. else vs nat
                int n2 = r - 96;
                if (k < 512) { int u = k & 63, vv = k >> 6; v = Wmsv[(u * 8 + vv) * 32 + n2] * INV_SQRT768; }
                else         { v = Wmvs[(k - 512) * 32 + n2] * INV_SQRT768; }
            }
        }
    } else if (i < 1040384) {               // updW1: [224][96][40] (+pad to 4096 elems/tile)
        int j = i - 122880;
        dst = (short*)(wout + UPDW1_OFF) + j;
        int t = j / 4096, q = j % 4096, r = q / 40, c = q % 40;
        if (q < 3840 && c < 32) {
            int k = t * 32 + c;
            if (k < 6144) { int u = k & 63, vv = k >> 6;          // ss REORDERED k=v*64+u
                v = Wuss[(u * 96 + vv) * 96 + r] * INV_SQRT7168; }
            else { int r2 = k - 6144; int u = r2 & 31, vv = r2 >> 5;  // vv REORDERED k=v*32+u
                v = Wuvv[(u * 32 + vv) * 96 + r] * (INV_SQRT3 * INV_SQRT7168); }
        }
    } else if (i < 1286144) {               // updW2: [160][32][40] (+pad to 1536)
        int j = i - 1040384;
        dst = (short*)(wout + UPDW2_OFF) + j;
        int t = j / 1536, q = j % 1536, r = q / 40, c = q % 40;
        if (q < 1280 && c < 32) {
            int k = t * 32 + c;
            if (k < 2048) { int u = k & 63, vv = k >> 6;          // sv REORDERED k=v*64+u
                v = Wusv[(u * 32 + vv) * 32 + r] * INV_SQRT5120; }
            else { int r2 = k - 2048;                              // vs natural u*96+v
                v = Wuvs[r2 * 32 + r] * INV_SQRT5120; }
        }
    } else if (i < 1294336) {               // mLin: WlsT [96][72] then WlvT [32][40]
        int j = i - 1286144;
        dst = (short*)(wout + MLIN_OFF) + j;
        if (j < 6912) { int n = j / 72, kk = j % 72; if (kk < 64) v = Wlms[kk * 96 + n] * 0.125f; }
        else { int j2 = j - 6912; int n = j2 / 40, kk = j2 % 40; if (kk < 32) v = Wlmv[kk * 32 + n] * INV_SQRT32; }
    } else if (i < 1300480) {               // uLin: WlsT [64][72] then WlvT [32][40]
        int j = i - 1294336;
        dst = (short*)(wout + ULIN_OFF) + j;
        if (j < 4608) { int n = j / 72, kk = j % 72; if (kk < 64) v = Wlus[kk * 64 + n] * 0.125f; }
        else if (j < 5888) { int j2 = j - 4608; int n = j2 / 40, kk = j2 % 40; if (kk < 32) v = Wluv[kk * 32 + n] * INV_SQRT32; }
        else v = 0.f;
    } else return;
    *dst = f2bf(v);
}

// ================= message kernel: 32 edges/block, 4 waves, MFMA =================
__global__ __launch_bounds__(256, 2) void msg_kernel(
    const float* __restrict__ nf, const float* __restrict__ ea,
    const int* __restrict__ eidx, const char* __restrict__ wout,
    float* __restrict__ agg)
{
    __shared__ char pool[79488];
    float* nf_sh  = (float*)pool;                  // [32][164] f32
    float* ea_sh  = (float*)(pool + 20992);        // [32][36]
    int*   row_sh = (int*)  (pool + 25600);        // [32]
    short* wbuf   = (short*)(pool + 25728);        // [2][5120]: W1t[96][40] + W2t[32][40]
    short* lin    = (short*)(pool + 46208);        // [8192]: WlsT[96][72], WlvT @6912
    float* gat    = (float*)(pool + 62592);        // [32][36]
    short* silu_s = (short*)(pool + 67200);        // [32][72] bf16
    short* pv_s   = (short*)(pool + 71808);        // [96][40] bf16  (rows = m*32+e)

    const int t = threadIdx.x, w = t >> 6, lane = t & 63;
    const int l15 = lane & 15, lg = lane >> 4;     // lg in [0,4): k-group
    const int eblk = blockIdx.x * 32;

    const char* msgW = wout + MSGW_OFF;
    const char* mlin = wout + MLIN_OFF;

    // issue epilogue-linear weights (16KB) + K-tile 0 (10KB) async
    for (int c = w; c < 16; c += 4) gl2lds(mlin + c * 1024 + lane * 16, (char*)lin + c * 1024);
    for (int c = w; c < 10; c += 4) gl2lds(msgW + c * 1024 + lane * 16, (char*)wbuf + c * 1024);

    {   // stage gathered src-node rows + edge attrs (f32)
        const int i = t >> 3, j = t & 7;
        const int e = eblk + i;
        if (j == 0) row_sh[i] = eidx[e];
        const int col = eidx[kEdges + e];
        const float4* src = (const float4*)(nf + (size_t)col * 160);
        for (int c = j; c < 40; c += 8) *(float4*)&nf_sh[i * 164 + c * 4] = src[c];
        const float4* esrc = (const float4*)(ea + (size_t)e * 32);
        *(float4*)&ea_sh[i * 36 + j * 4] = esrc[j];
    }
    __syncthreads();

    // ---- main K-loop: 24 tiles of K=32. scalar GEMM [32,768]@[768,96],
    //      vector GEMM [96(m,e),768]@[768,32]. per wave: 3 scalar + 3 vector C-tiles.
    f4 accS[3] = {{0.f,0.f,0.f,0.f},{0.f,0.f,0.f,0.f},{0.f,0.f,0.f,0.f}};
    f4 accV[3] = {{0.f,0.f,0.f,0.f},{0.f,0.f,0.f,0.f},{0.f,0.f,0.f,0.f}};
    const int Ms = w >> 1, nb = (w & 1) * 3;       // scalar M-tile, n-tile base
    const int es_ = Ms * 16 + l15;                 // scalar A row (edge)

    // hoist scalar-path edge operands (row es_) into registers: 8 + 24 f32
    const float4 ey0 = *(const float4*)&ea_sh[es_ * 36];
    const float4 ey1 = *(const float4*)&ea_sh[es_ * 36 + 4];
    float eyv[24];
    #pragma unroll
    for (int q = 0; q < 6; ++q)
        *(float4*)&eyv[q * 4] = *(const float4*)&ea_sh[es_ * 36 + 8 + q * 4];

    for (int kt = 0; kt < 24; ++kt) {
        const short* wb = wbuf + (kt & 1) * 5120;
        if (kt + 1 < 24)                            // prefetch next K-tile
            for (int c = w; c < 10; c += 4)
                gl2lds(msgW + (kt + 1) * 10240 + c * 1024 + lane * 16,
                       (char*)(wbuf + ((kt + 1) & 1) * 5120) + c * 1024);

        // scalar A-frag: k = kt*32 + lg*8 + j
        BF aS;
        if (kt < 16) {                              // ss: A[j] = xs[u] * ys[j]
            const int uu = kt * 4 + lg;
            const float xs = nf_sh[es_ * 164 + uu];
            aS.u[0] = pk2(xs * ey0.x, xs * ey0.y);
            aS.u[1] = pk2(xs * ey0.z, xs * ey0.w);
            aS.u[2] = pk2(xs * ey1.x, xs * ey1.y);
            aS.u[3] = pk2(xs * ey1.z, xs * ey1.w);
        } else {                                    // vv: A[j] = dot(xv[u], yv[j]) (w3j folded in W)
            const int uu = (kt - 16) * 4 + lg;
            const float* xp = &nf_sh[es_ * 164 + 64 + 3 * uu];
            const float x0 = xp[0], x1 = xp[1], x2 = xp[2];
            #pragma unroll
            for (int j = 0; j < 4; ++j) {
                float a0 = x0 * eyv[6*j  ] + x1 * eyv[6*j+1] + x2 * eyv[6*j+2];
                float a1 = x0 * eyv[6*j+3] + x1 * eyv[6*j+4] + x2 * eyv[6*j+5];
                aS.u[j] = pk2(a0, a1);
            }
        }
        #pragma unroll
        for (int i = 0; i < 3; ++i) {
            bf8 b = *(const bf8*)&wb[((nb + i) * 16 + l15) * 40 + lg * 8];
            accS[i] = mfma16(aS.v, b, accS[i]);
        }

        // vector tiles: tv = 3w+i -> Mv = tv>>1 (row-tile: m = Mv>>1, e-half = Mv&1), Nv = tv&1
        BF aV; int prevMv = -1;
        #pragma unroll
        for (int i = 0; i < 3; ++i) {
            const int tv = 3 * w + i, Mv = tv >> 1, Nv = tv & 1;
            if (Mv != prevMv) {
                prevMv = Mv;
                const int m = Mv >> 1, ev = (Mv & 1) * 16 + l15;
                if (kt < 16) {                      // sv (k reordered v*64+u): A[j] = xs[u0+j]*yv[v][m]
                    const int kp = kt * 32 + lg * 8;
                    const int vv = kp >> 6, u0 = kp & 63;
                    const float ym = ea_sh[ev * 36 + 8 + 3 * vv + m];
                    const float4 x0 = *(const float4*)&nf_sh[ev * 164 + u0];
                    const float4 x1 = *(const float4*)&nf_sh[ev * 164 + u0 + 4];
                    aV.u[0] = pk2(x0.x * ym, x0.y * ym);
                    aV.u[1] = pk2(x0.z * ym, x0.w * ym);
                    aV.u[2] = pk2(x1.x * ym, x1.y * ym);
                    aV.u[3] = pk2(x1.z * ym, x1.w * ym);
                } else {                            // vs (natural u*8+v): A[j] = xv[u][m]*ys[j]
                    const int uu = (kt - 16) * 4 + lg;
                    const float xm = nf_sh[ev * 164 + 64 + 3 * uu + m];
                    const float4 y0 = *(const float4*)&ea_sh[ev * 36];
                    const float4 y1 = *(const float4*)&ea_sh[ev * 36 + 4];
                    aV.u[0] = pk2(xm * y0.x, xm * y0.y);
                    aV.u[1] = pk2(xm * y0.z, xm * y0.w);
                    aV.u[2] = pk2(xm * y1.x, xm * y1.y);
                    aV.u[3] = pk2(xm * y1.z, xm * y1.w);
                }
            }
            bf8 b = *(const bf8*)&wb[3840 + (Nv * 16 + l15) * 40 + lg * 8];
            accV[i] = mfma16(aV.v, b, accV[i]);
        }
        __syncthreads();
    }

    // ---- epilogue: silu/gates from scalar C (rows e = Ms*16 + lg*4 + r, col n)
    #pragma unroll
    for (int i = 0; i < 3; ++i) {
        const int n = (nb + i) * 16 + l15;
        #pragma unroll
        for (int r = 0; r < 4; ++r) {
            const int e = Ms * 16 + lg * 4 + r;
            const float v = accS[i][r];
            if (n < 64) silu_s[e * 72 + n] = f2bf(v * fsig(v));
            else        gat[e * 36 + (n - 64)] = fsig(v);
        }
    }
    __syncthreads();
    // gate vectors -> pv (bf16)
    #pragma unroll
    for (int i = 0; i < 3; ++i) {
        const int tv = 3 * w + i, Mv = tv >> 1, Nv = tv & 1;
        const int m = Mv >> 1, eb = (Mv & 1) * 16;
        const int u = Nv * 16 + l15;
        #pragma unroll
        for (int r = 0; r < 4; ++r) {
            const int e = eb + lg * 4 + r;
            pv_s[(m * 32 + e) * 40 + u] = f2bf(accV[i][r] * gat[e * 36 + u]);
        }
    }
    __syncthreads();

    // ---- linear (MFMA) + fused atomic scatter. scales folded into weights.
    {   // ls: [32,64] @ WlsT -> [32,96]
        f4 acc[3] = {{0.f,0.f,0.f,0.f},{0.f,0.f,0.f,0.f},{0.f,0.f,0.f,0.f}};
        #pragma unroll
        for (int k0 = 0; k0 < 2; ++k0) {
            const int kg = k0 * 32 + lg * 8;
            bf8 a = *(const bf8*)&silu_s[es_ * 72 + kg];
            #pragma unroll
            for (int i = 0; i < 3; ++i) {
                bf8 b = *(const bf8*)&lin[((nb + i) * 16 + l15) * 72 + kg];
                acc[i] = mfma16(a, b, acc[i]);
            }
        }
        #pragma unroll
        for (int i = 0; i < 3; ++i) {
            const int n = (nb + i) * 16 + l15;
            #pragma unroll
            for (int r = 0; r < 4; ++r) {
                const int e = Ms * 16 + lg * 4 + r;
                atomicAdd(&agg[(size_t)row_sh[e] * 192 + n], acc[i][r]);
            }
        }
    }
    {   // lv: [96,32] @ WlvT -> [96,32]; rows rr -> (m = rr>>5, e = rr&31)
        f4 acc[3] = {{0.f,0.f,0.f,0.f},{0.f,0.f,0.f,0.f},{0.f,0.f,0.f,0.f}};
        const int kg = lg * 8;
        BF a; int prevMv = -1;
        #pragma unroll
        for (int i = 0; i < 3; ++i) {
            const int tv = 3 * w + i, Mv = tv >> 1, Nv = tv & 1;
            if (Mv != prevMv) { prevMv = Mv; a.v = *(const bf8*)&pv_s[(Mv * 16 + l15) * 40 + kg]; }
            bf8 b = *(const bf8*)&lin[6912 + (Nv * 16 + l15) * 40 + kg];
            acc[i] = mfma16(a.v, b, acc[i]);
        }
        #pragma unroll
        for (int i = 0; i < 3; ++i) {
            const int tv = 3 * w + i, Mv = tv >> 1, Nv = tv & 1;
            const int w2 = Nv * 16 + l15;
            #pragma unroll
            for (int r = 0; r < 4; ++r) {
                const int rr = Mv * 16 + lg * 4 + r;
                const int m = rr >> 5, e = rr & 31;
                atomicAdd(&agg[(size_t)row_sh[e] * 192 + 96 + w2 * 3 + m], acc[i][r]);
            }
        }
    }
}

// ================= update kernel: 32 nodes/block, 8 waves, K-split-2, MFMA ===========
// Wave-group g (waves 4g..4g+3) computes the K-half [g*half, (g+1)*half); partials
// reduced via LDS. Result (residual+delta) written into agg rows (cols 0..159).
__global__ __launch_bounds__(512, 1) void upd_kernel(
    const float* __restrict__ nf, const char* __restrict__ wout,
    float* __restrict__ agg)
{
    __shared__ char pool[140800];
    float* nf_sh  = (float*)pool;                  // [32][164]
    float* ag_sh  = (float*)(pool + 20992);        // [32][196]
    short* wbuf   = (short*)(pool + 46080);        // 64KB: per-group 32KB double-buffered stages
    short* lin    = (short*)(pool + 111616);       // [6144]: WlsT[64][72], WlvT @4608
    float* gat    = (float*)(pool + 123904);       // [32][36]
    short* silu_s = (short*)(pool + 128512);       // [32][72]
    short* gv_s   = (short*)(pool + 133120);       // [96][40]
    float* red    = (float*)(pool + 46080);        // reduction scratch (reuses wbuf)

    const int t = threadIdx.x, w = t >> 6, lane = t & 63;
    const int g = w >> 2, wl = w & 3;              // K-half group, local wave
    const int l15 = lane & 15, lg = lane >> 4;
    const int nblk = blockIdx.x * 32;
    const char* W1 = wout + UPDW1_OFF;
    const char* W2 = wout + UPDW2_OFF;
    short* const gw = wbuf + g * 16384;            // this group's 32KB staging region

    for (int c = w; c < 12; c += 8) gl2lds(wout + ULIN_OFF + c * 1024 + lane * 16, (char*)lin + c * 1024);
    // scalar stage 0: each group stages its first 2 K-tiles (16KB)
    for (int c = wl; c < 16; c += 4)
        gl2lds(W1 + (size_t)g * 112 * 8192 + c * 1024 + lane * 16, (char*)gw + c * 1024);

    {   // stage node rows + agg rows (clamp tail)
        const int i = t >> 4, j = t & 15;
        int n = nblk + i; if (n > kNodes - 1) n = kNodes - 1;
        const float4* src = (const float4*)(nf + (size_t)n * 160);
        for (int c = j; c < 40; c += 16) *(float4*)&nf_sh[i * 164 + c * 4] = src[c];
        const float4* asrc = (const float4*)(agg + (size_t)n * 192);
        for (int c = j; c < 48; c += 16) *(float4*)&ag_sh[i * 196 + c * 4] = asrc[c];
    }
    __syncthreads();

    const int Ms = wl >> 1, nb = (wl & 1) * 3;
    const int es_ = Ms * 16 + l15;

    // ---- scalar K-loop: group g covers tiles [g*112, g*112+112), 56 stages of 2.
    //      K<6144: ss (v*64+u); else vv (v*32+u)
    f4 accS[3] = {{0.f,0.f,0.f,0.f},{0.f,0.f,0.f,0.f},{0.f,0.f,0.f,0.f}};
    for (int s = 0; s < 56; ++s) {
        if (s + 1 < 56)
            for (int c = wl; c < 16; c += 4)
                gl2lds(W1 + (size_t)(g * 112 + (s + 1) * 2) * 8192 + c * 1024 + lane * 16,
                       (char*)(gw + ((s + 1) & 1) * 8192) + c * 1024);
        #pragma unroll
        for (int tl = 0; tl < 2; ++tl) {
            const int kt = g * 112 + s * 2 + tl;
            const short* wb = gw + (s & 1) * 8192 + tl * 4096;
            BF aS;
            if (kt < 192) {                          // A[j] = ns[u0+j] * agg_s[v]
                const int kp = kt * 32 + lg * 8;
                const int vv = kp >> 6, u0 = kp & 63;
                const float ys = ag_sh[es_ * 196 + vv];
                const float4 x0 = *(const float4*)&nf_sh[es_ * 164 + u0];
                const float4 x1 = *(const float4*)&nf_sh[es_ * 164 + u0 + 4];
                aS.u[0] = pk2(x0.x * ys, x0.y * ys);
                aS.u[1] = pk2(x0.z * ys, x0.w * ys);
                aS.u[2] = pk2(x1.x * ys, x1.y * ys);
                aS.u[3] = pk2(x1.z * ys, x1.w * ys);
            } else {                                 // A[j] = dot(nv[u0+j], agg_v[v])
                const int rp = kt * 32 + lg * 8 - 6144;
                const int vv = rp >> 5, u0 = rp & 31;
                const float* xp = &nf_sh[es_ * 164 + 64 + 3 * u0];
                const float* gp = &ag_sh[es_ * 196 + 96 + 3 * vv];
                const float g0 = gp[0], g1 = gp[1], g2 = gp[2];
                #pragma unroll
                for (int j = 0; j < 4; ++j) {
                    float a0 = xp[6*j  ] * g0 + xp[6*j+1] * g1 + xp[6*j+2] * g2;
                    float a1 = xp[6*j+3] * g0 + xp[6*j+4] * g1 + xp[6*j+5] * g2;
                    aS.u[j] = pk2(a0, a1);
                }
            }
            #pragma unroll
            for (int i = 0; i < 3; ++i) {
                bf8 b = *(const bf8*)&wb[((nb + i) * 16 + l15) * 40 + lg * 8];
                accS[i] = mfma16(aS.v, b, accS[i]);
            }
        }
        __syncthreads();
    }

    // ---- scalar reduce (group1 -> LDS, group0 adds) + silu/gate epilogue
    if (g == 1) {
        #pragma unroll
        for (int i = 0; i < 3; ++i) {
            const int n = (nb + i) * 16 + l15;
            #pragma unroll
            for (int r = 0; r < 4; ++r)
                red[(Ms * 16 + lg * 4 + r) * 96 + n] = accS[i][r];
        }
    }
    __syncthreads();
    if (g == 0) {
        #pragma unroll
        for (int i = 0; i < 3; ++i) {
            const int n = (nb + i) * 16 + l15;
            #pragma unroll
            for (int r = 0; r < 4; ++r) {
                const int e = Ms * 16 + lg * 4 + r;
                const float v = accS[i][r] + red[e * 96 + n];
                if (n < 64) silu_s[e * 72 + n] = f2bf(v * fsig(v));
                else        gat[e * 36 + (n - 64)] = fsig(v);
            }
        }
    }
    __syncthreads();                                 // red consumed; wbuf reusable
    // vector stage 0: each group stages its first 4 K-tiles (12KB)
    for (int c = wl; c < 12; c += 4)
        gl2lds(W2 + (size_t)g * 80 * 3072 + c * 1024 + lane * 16, (char*)gw + c * 1024);
    __syncthreads();

    // ---- vector K-loop: group g covers tiles [g*80, g*80+80), 20 stages of 4.
    //      K<2048: sv (v*64+u); else vs (u*96+v)
    f4 accV[3] = {{0.f,0.f,0.f,0.f},{0.f,0.f,0.f,0.f},{0.f,0.f,0.f,0.f}};
    for (int s = 0; s < 20; ++s) {
        if (s + 1 < 20)
            for (int c = wl; c < 12; c += 4)
                gl2lds(W2 + (size_t)(g * 80 + (s + 1) * 4) * 3072 + c * 1024 + lane * 16,
                       (char*)(gw + ((s + 1) & 1) * 6144) + c * 1024);
        #pragma unroll
        for (int tl = 0; tl < 4; ++tl) {
            const int kt = g * 80 + s * 4 + tl;
            const short* wb = gw + (s & 1) * 6144 + tl * 1536;
            BF aV; int prevMv = -1;
            #pragma unroll
            for (int i = 0; i < 3; ++i) {
                const int tv = 3 * wl + i, Mv = tv >> 1, Nv = tv & 1;
                if (Mv != prevMv) {
                    prevMv = Mv;
                    const int m = Mv >> 1, ev = (Mv & 1) * 16 + l15;
                    if (kt < 64) {                   // A[j] = ns[u0+j] * agg_v[v][m]
                        const int kp = kt * 32 + lg * 8;
                        const int vv = kp >> 6, u0 = kp & 63;
                        const float ym = ag_sh[ev * 196 + 96 + 3 * vv + m];
                        const float4 x0 = *(const float4*)&nf_sh[ev * 164 + u0];
                        const float4 x1 = *(const float4*)&nf_sh[ev * 164 + u0 + 4];
                        aV.u[0] = pk2(x0.x * ym, x0.y * ym);
                        aV.u[1] = pk2(x0.z * ym, x0.w * ym);
                        aV.u[2] = pk2(x1.x * ym, x1.y * ym);
                        aV.u[3] = pk2(x1.z * ym, x1.w * ym);
                    } else {                         // A[j] = nv[u][m] * agg_s[v0+j]
                        const int rp = kt * 32 + lg * 8 - 2048;
                        const int u = rp / 96, v0 = rp - u * 96;
                        const float xm = nf_sh[ev * 164 + 64 + 3 * u + m];
                        const float4 y0 = *(const float4*)&ag_sh[ev * 196 + v0];
                        const float4 y1 = *(const float4*)&ag_sh[ev * 196 + v0 + 4];
                        aV.u[0] = pk2(xm * y0.x, xm * y0.y);
                        aV.u[1] = pk2(xm * y0.z, xm * y0.w);
                        aV.u[2] = pk2(xm * y1.x, xm * y1.y);
                        aV.u[3] = pk2(xm * y1.z, xm * y1.w);
                    }
                }
                bf8 b = *(const bf8*)&wb[(Nv * 16 + l15) * 40 + lg * 8];
                accV[i] = mfma16(aV.v, b, accV[i]);
            }
        }
        __syncthreads();
    }

    // ---- vector reduce (group1 -> LDS, group0 adds) + gate -> gv
    if (g == 1) {
        #pragma unroll
        for (int i = 0; i < 3; ++i) {
            const int tv = 3 * wl + i, Mv = tv >> 1, Nv = tv & 1;
            #pragma unroll
            for (int r = 0; r < 4; ++r)
                red[(Mv * 16 + lg * 4 + r) * 32 + Nv * 16 + l15] = accV[i][r];
        }
    }
    __syncthreads();
    if (g == 0) {
        #pragma unroll
        for (int i = 0; i < 3; ++i) {
            const int tv = 3 * wl + i, Mv = tv >> 1, Nv = tv & 1;
            const int m = Mv >> 1, eb = (Mv & 1) * 16;
            const int u = Nv * 16 + l15;
            #pragma unroll
            for (int r = 0; r < 4; ++r) {
                const int e = eb + lg * 4 + r;
                const float v = accV[i][r] + red[(Mv * 16 + lg * 4 + r) * 32 + u];
                gv_s[(m * 32 + e) * 40 + u] = f2bf(v * gat[e * 36 + u]);
            }
        }
    }
    __syncthreads();

    // ---- final linears (MFMA) + residual -> agg rows (cols 0..159); group 0 only
    const int nvalid = kNodes - nblk;
    if (g == 0) {
        {   // ds: [32,64] @ WlsT_u -> [32,64]; 2M x 4N tiles, 2 per wave
            f4 acc[2] = {{0.f,0.f,0.f,0.f},{0.f,0.f,0.f,0.f}};
            const int nb2 = (wl & 1) * 2;
            #pragma unroll
            for (int k0 = 0; k0 < 2; ++k0) {
                const int kg = k0 * 32 + lg * 8;
                bf8 a = *(const bf8*)&silu_s[es_ * 72 + kg];
                #pragma unroll
                for (int i = 0; i < 2; ++i) {
                    bf8 b = *(const bf8*)&lin[((nb2 + i) * 16 + l15) * 72 + kg];
                    acc[i] = mfma16(a, b, acc[i]);
                }
            }
            #pragma unroll
            for (int i = 0; i < 2; ++i) {
                const int n = (nb2 + i) * 16 + l15;
                #pragma unroll
                for (int r = 0; r < 4; ++r) {
                    const int e = Ms * 16 + lg * 4 + r;
                    if (e < nvalid)
                        agg[(size_t)(nblk + e) * 192 + n] = nf_sh[e * 164 + n] + acc[i][r];
                }
            }
        }
        {   // dv: [96,32] @ WlvT_u -> [96,32]
            f4 acc[3] = {{0.f,0.f,0.f,0.f},{0.f,0.f,0.f,0.f},{0.f,0.f,0.f,0.f}};
            const int kg = lg * 8;
            BF a; int prevMv = -1;
            #pragma unroll
            for (int i = 0; i < 3; ++i) {
                const int tv = 3 * wl + i, Mv = tv >> 1, Nv = tv & 1;
                if (Mv != prevMv) { prevMv = Mv; a.v = *(const bf8*)&gv_s[(Mv * 16 + l15) * 40 + kg]; }
                bf8 b = *(const bf8*)&lin[4608 + (Nv * 16 + l15) * 40 + kg];
                acc[i] = mfma16(a.v, b, acc[i]);
            }
            #pragma unroll
            for (int i = 0; i < 3; ++i) {
                const int tv = 3 * wl + i, Mv = tv >> 1, Nv = tv & 1;
                const int w2 = Nv * 16 + l15;
                #pragma unroll
                for (int r = 0; r < 4; ++r) {
                    const int rr = Mv * 16 + lg * 4 + r;
                    const int m = rr >> 5, e = rr & 31;
                    if (e < nvalid)
                        agg[(size_t)(nblk + e) * 192 + 64 + w2 * 3 + m]
                            = nf_sh[e * 164 + 64 + w2 * 3 + m] + acc[i][r];
                }
            }
        }
    }
}

// ================= final copy: agg rows (cols 0..159) -> d_out [10000][160] ==========
__global__ __launch_bounds__(256) void copy_kernel(const float* __restrict__ agg,
                                                   float* __restrict__ out)
{
    int i = blockIdx.x * 256 + threadIdx.x;       // i indexes [10000][40] float4s
    if (i < 400000) {
        int n = i / 40, c = i - n * 40;
        ((float4*)out)[i] = ((const float4*)agg)[n * 48 + c];
    }
}

extern "C" void kernel_launch(void* const* d_in, const int* in_sizes, int n_in,
                              void* d_out, int out_size, void* d_ws, size_t ws_size,
                              hipStream_t stream) {
    const float* nf   = (const float*)d_in[0];
    const float* ea   = (const float*)d_in[1];
    const int*   eidx = (const int*)d_in[14];
    float* agg = (float*)d_ws;                     // f32 [10000][192] — ONLY ws use
    char*  wout = (char*)d_out;                    // weights live here until final copy

    hipMemsetAsync(agg, 0, 7680000, stream);
    prep_kernel<<<5080, 256, 0, stream>>>(
        (const float*)d_in[2], (const float*)d_in[3], (const float*)d_in[4],
        (const float*)d_in[5], (const float*)d_in[6], (const float*)d_in[7],
        (const float*)d_in[8], (const float*)d_in[9], (const float*)d_in[10],
        (const float*)d_in[11], (const float*)d_in[12], (const float*)d_in[13], wout);
    msg_kernel<<<kEdges / 32, 256, 0, stream>>>(nf, ea, eidx, wout, agg);
    upd_kernel<<<(kNodes + 31) / 32, 512, 0, stream>>>(nf, wout, agg);
    copy_kernel<<<1563, 256, 0, stream>>>(agg, (float*)d_out);
}

// Round 7
// 463.328 us; speedup vs baseline: 7.2319x; 1.1316x over previous
//
#include <hip/hip_runtime.h>
#include <hip/hip_bf16.h>

// irreps: node = 64x0e + 32x1o (160 f32), edge = 8x0e + 8x1o (32 f32)
// hidden = 96x0e + 32x1o ; agg row = 96 scalars + 32*3 vectors = 192 f32
constexpr int kNodes = 10000;
constexpr int kEdges = 100000;

constexpr float INV_SQRT3    = 0.57735026918962576f;
constexpr float INV_SQRT768  = 0.036084391824351615f;  // msg fan
constexpr float INV_SQRT7168 = 0.011811389781538352f;  // upd scalar fan
constexpr float INV_SQRT5120 = 0.013975424859373686f;  // upd vector fan
constexpr float INV_SQRT32   = 0.17677669529663687f;

// d_ws: ONLY the f32 agg accumulator [10000][192] = 7,680,000 B (proven safe size).
// Prepped bf16 weights (unpadded, 64B rows) live in d_out until the final copy:
constexpr size_t MSGW_OFF  = 0;         // 24 x [128][32] bf16 = 196,608 B
constexpr size_t UPDW1_OFF = 196608;    // 224 x [96][32]      = 1,376,256 B
constexpr size_t UPDW2_OFF = 1572864;   // 160 x [32][32]      = 327,680 B
constexpr size_t MLINS_OFF = 1900544;   // [96][64]            = 12,288 B
constexpr size_t MLINV_OFF = 1912832;   // [32][32]            = 2,048 B
constexpr size_t ULINS_OFF = 1914880;   // [64][64]            = 8,192 B
constexpr size_t ULINV_OFF = 1923072;   // [32][32]            = 2,048 B  (end 1,925,120 < 6.4MB)

typedef __attribute__((ext_vector_type(8))) short bf8;  // 8 bf16 (4 VGPR) MFMA operand
typedef __attribute__((ext_vector_type(4))) float f4;   // MFMA accumulator
union BF { bf8 v; short s[8]; unsigned u[4]; };

__device__ __forceinline__ short f2bf(float f) {   // RNE f32->bf16 (cold paths)
    union { float f; unsigned u; } c; c.f = f;
    unsigned r = c.u + 0x7fffu + ((c.u >> 16) & 1u);
    return (short)(r >> 16);
}
__device__ __forceinline__ unsigned pk2(float lo, float hi) {  // v_cvt_pk_bf16_f32
    union { __hip_bfloat162 h; unsigned u; } c;
    c.h = __float22bfloat162_rn(make_float2(lo, hi));
    return c.u;
}
__device__ __forceinline__ f4 mfma16(bf8 a, bf8 b, f4 c) {
    return __builtin_amdgcn_mfma_f32_16x16x32_bf16(a, b, c, 0, 0, 0);
}
__device__ __forceinline__ bf8 ldB(const char* p) {  // direct L2-served B-fragment
    return *(const bf8*)p;
}
__device__ __forceinline__ float fsig(float x) { return 1.0f / (1.0f + __expf(-x)); }

// ================= prep: scale + transpose + reorder weights to bf16 (into d_out) ==========
__global__ void prep_kernel(
    const float* __restrict__ Wmss, const float* __restrict__ Wmvv,
    const float* __restrict__ Wmsv, const float* __restrict__ Wmvs,
    const float* __restrict__ Wlms, const float* __restrict__ Wlmv,
    const float* __restrict__ Wuss, const float* __restrict__ Wuvv,
    const float* __restrict__ Wusv, const float* __restrict__ Wuvs,
    const float* __restrict__ Wlus, const float* __restrict__ Wluv,
    char* __restrict__ wout)
{
    int i = blockIdx.x * 256 + threadIdx.x;
    float v;
    short* dst;
    if (i < 98304) {                        // msgW: [24][128][32]
        dst = (short*)(wout + MSGW_OFF) + i;
        int t = i >> 12, q = i & 4095, r = q >> 5, c = q & 31;
        int k = t * 32 + c;
        if (r < 96) {                       // W1: k<512 ss (k=u*8+v); else vv natural
            v = (k < 512 ? Wmss[k * 96 + r]
                         : Wmvv[(k - 512) * 96 + r] * INV_SQRT3) * INV_SQRT768;
        } else {                            // W2: k<512 sv REORDERED k=v*64+u; else vs natural
            int n2 = r - 96;
            if (k < 512) { int u = k & 63, vv = k >> 6; v = Wmsv[(u * 8 + vv) * 32 + n2] * INV_SQRT768; }
            else         { v = Wmvs[(k - 512) * 32 + n2] * INV_SQRT768; }
        }
    } else if (i < 786432) {                // updW1: [224][96][32]
        int j = i - 98304;
        dst = (short*)(wout + UPDW1_OFF) + j;
        int t = j / 3072, q = j % 3072, r = q >> 5, c = q & 31;
        int k = t * 32 + c;
        if (k < 6144) { int u = k & 63, vv = k >> 6;              // ss REORDERED k=v*64+u
            v = Wuss[(u * 96 + vv) * 96 + r] * INV_SQRT7168; }
        else { int r2 = k - 6144; int u = r2 & 31, vv = r2 >> 5;  // vv REORDERED k=v*32+u
            v = Wuvv[(u * 32 + vv) * 96 + r] * (INV_SQRT3 * INV_SQRT7168); }
    } else if (i < 950272) {                // updW2: [160][32][32]
        int j = i - 786432;
        dst = (short*)(wout + UPDW2_OFF) + j;
        int t = j >> 10, q = j & 1023, r = q >> 5, c = q & 31;
        int k = t * 32 + c;
        if (k < 2048) { int u = k & 63, vv = k >> 6;              // sv REORDERED k=v*64+u
            v = Wusv[(u * 32 + vv) * 32 + r] * INV_SQRT5120; }
        else { int r2 = k - 2048;                                  // vs natural u*96+v
            v = Wuvs[r2 * 32 + r] * INV_SQRT5120; }
    } else if (i < 956416) {                // mlin_s: [96][64]
        int j = i - 950272;
        dst = (short*)(wout + MLINS_OFF) + j;
        int n = j >> 6, kk = j & 63;
        v = Wlms[kk * 96 + n] * 0.125f;
    } else if (i < 957440) {                // mlin_v: [32][32]
        int j = i - 956416;
        dst = (short*)(wout + MLINV_OFF) + j;
        int n = j >> 5, kk = j & 31;
        v = Wlmv[kk * 32 + n] * INV_SQRT32;
    } else if (i < 961536) {                // ulin_s: [64][64]
        int j = i - 957440;
        dst = (short*)(wout + ULINS_OFF) + j;
        int n = j >> 6, kk = j & 63;
        v = Wlus[kk * 64 + n] * 0.125f;
    } else if (i < 962560) {                // ulin_v: [32][32]
        int j = i - 961536;
        dst = (short*)(wout + ULINV_OFF) + j;
        int n = j >> 5, kk = j & 31;
        v = Wluv[kk * 32 + n] * INV_SQRT32;
    } else return;
    *dst = f2bf(v);
}

// ================= message kernel: 32 edges/block, 4 waves, MFMA, no K-loop barriers ========
// B-operands read directly from global (L2-resident prepped weights).
__global__ __launch_bounds__(256, 3) void msg_kernel(
    const float* __restrict__ nf, const float* __restrict__ ea,
    const int* __restrict__ eidx, const char* __restrict__ wout,
    float* __restrict__ agg)
{
    __shared__ float nf_sh[32 * 164];    // 20992B
    __shared__ float ea_sh[32 * 36];     // 4608B
    __shared__ int   row_sh[32];         // 128B
    __shared__ float gat[32 * 36];       // 4608B
    __shared__ short silu_s[32 * 72];    // 4608B
    __shared__ short pv_s[96 * 40];      // 7680B   -> total ~42.6KB => 3 blocks/CU

    const int t = threadIdx.x, w = t >> 6, lane = t & 63;
    const int l15 = lane & 15, lg = lane >> 4;     // lg in [0,4): k-group
    const int eblk = blockIdx.x * 32;

    const char* msgW = wout + MSGW_OFF;

    {   // stage gathered src-node rows + edge attrs (f32)
        const int i = t >> 3, j = t & 7;
        const int e = eblk + i;
        if (j == 0) row_sh[i] = eidx[e];
        const int col = eidx[kEdges + e];
        const float4* src = (const float4*)(nf + (size_t)col * 160);
        for (int c = j; c < 40; c += 8) *(float4*)&nf_sh[i * 164 + c * 4] = src[c];
        const float4* esrc = (const float4*)(ea + (size_t)e * 32);
        *(float4*)&ea_sh[i * 36 + j * 4] = esrc[j];
    }
    __syncthreads();

    // ---- main K-loop: 24 tiles of K=32, NO barriers. scalar GEMM [32,768]@[768,96],
    //      vector GEMM [96(m,e),768]@[768,32]. per wave: 3 scalar + 3 vector C-tiles.
    f4 accS[3] = {{0.f,0.f,0.f,0.f},{0.f,0.f,0.f,0.f},{0.f,0.f,0.f,0.f}};
    f4 accV[3] = {{0.f,0.f,0.f,0.f},{0.f,0.f,0.f,0.f},{0.f,0.f,0.f,0.f}};
    const int Ms = w >> 1, nb = (w & 1) * 3;       // scalar M-tile, n-tile base
    const int es_ = Ms * 16 + l15;                 // scalar A row (edge)

    // hoist scalar-path edge operands (row es_) into registers: 8 + 24 f32
    const float4 ey0 = *(const float4*)&ea_sh[es_ * 36];
    const float4 ey1 = *(const float4*)&ea_sh[es_ * 36 + 4];
    float eyv[24];
    #pragma unroll
    for (int q = 0; q < 6; ++q)
        *(float4*)&eyv[q * 4] = *(const float4*)&ea_sh[es_ * 36 + 8 + q * 4];

    // phase 1: kt 0..15  (scalar=ss, vector=sv)
    for (int kt = 0; kt < 16; ++kt) {
        const char* wb = msgW + kt * 8192;
        BF aS;                                      // ss: A[j] = xs[u] * ys[j]
        {
            const int uu = kt * 4 + lg;
            const float xs = nf_sh[es_ * 164 + uu];
            aS.u[0] = pk2(xs * ey0.x, xs * ey0.y);
            aS.u[1] = pk2(xs * ey0.z, xs * ey0.w);
            aS.u[2] = pk2(xs * ey1.x, xs * ey1.y);
            aS.u[3] = pk2(xs * ey1.z, xs * ey1.w);
        }
        #pragma unroll
        for (int i = 0; i < 3; ++i)
            accS[i] = mfma16(aS.v, ldB(wb + ((nb + i) * 16 + l15) * 64 + lg * 16), accS[i]);

        BF aV; int prevMv = -1;
        #pragma unroll
        for (int i = 0; i < 3; ++i) {
            const int tv = 3 * w + i, Mv = tv >> 1, Nv = tv & 1;
            if (Mv != prevMv) {
                prevMv = Mv;
                const int m = Mv >> 1, ev = (Mv & 1) * 16 + l15;
                const int kp = kt * 32 + lg * 8;    // sv (k=v*64+u): A[j]=xs[u0+j]*yv[v][m]
                const int vv = kp >> 6, u0 = kp & 63;
                const float ym = ea_sh[ev * 36 + 8 + 3 * vv + m];
                const float4 x0 = *(const float4*)&nf_sh[ev * 164 + u0];
                const float4 x1 = *(const float4*)&nf_sh[ev * 164 + u0 + 4];
                aV.u[0] = pk2(x0.x * ym, x0.y * ym);
                aV.u[1] = pk2(x0.z * ym, x0.w * ym);
                aV.u[2] = pk2(x1.x * ym, x1.y * ym);
                aV.u[3] = pk2(x1.z * ym, x1.w * ym);
            }
            accV[i] = mfma16(aV.v, ldB(wb + (96 + (Nv * 16 + l15)) * 64 + lg * 16), accV[i]);
        }
    }
    // phase 2: kt 16..23  (scalar=vv, vector=vs)
    for (int kt = 16; kt < 24; ++kt) {
        const char* wb = msgW + kt * 8192;
        BF aS;                                      // vv: A[j] = dot(xv[u], yv[j])
        {
            const int uu = (kt - 16) * 4 + lg;
            const float* xp = &nf_sh[es_ * 164 + 64 + 3 * uu];
            const float x0 = xp[0], x1 = xp[1], x2 = xp[2];
            #pragma unroll
            for (int j = 0; j < 4; ++j) {
                float a0 = x0 * eyv[6*j  ] + x1 * eyv[6*j+1] + x2 * eyv[6*j+2];
                float a1 = x0 * eyv[6*j+3] + x1 * eyv[6*j+4] + x2 * eyv[6*j+5];
                aS.u[j] = pk2(a0, a1);
            }
        }
        #pragma unroll
        for (int i = 0; i < 3; ++i)
            accS[i] = mfma16(aS.v, ldB(wb + ((nb + i) * 16 + l15) * 64 + lg * 16), accS[i]);

        BF aV; int prevMv = -1;
        #pragma unroll
        for (int i = 0; i < 3; ++i) {
            const int tv = 3 * w + i, Mv = tv >> 1, Nv = tv & 1;
            if (Mv != prevMv) {
                prevMv = Mv;
                const int m = Mv >> 1, ev = (Mv & 1) * 16 + l15;
                const int uu = (kt - 16) * 4 + lg;  // vs (k=u*8+v): A[j]=xv[u][m]*ys[j]
                const float xm = nf_sh[ev * 164 + 64 + 3 * uu + m];
                const float4 y0 = *(const float4*)&ea_sh[ev * 36];
                const float4 y1 = *(const float4*)&ea_sh[ev * 36 + 4];
                aV.u[0] = pk2(xm * y0.x, xm * y0.y);
                aV.u[1] = pk2(xm * y0.z, xm * y0.w);
                aV.u[2] = pk2(xm * y1.x, xm * y1.y);
                aV.u[3] = pk2(xm * y1.z, xm * y1.w);
            }
            accV[i] = mfma16(aV.v, ldB(wb + (96 + (Nv * 16 + l15)) * 64 + lg * 16), accV[i]);
        }
    }

    // ---- epilogue: silu/gates from scalar C (rows e = Ms*16 + lg*4 + r, col n)
    #pragma unroll
    for (int i = 0; i < 3; ++i) {
        const int n = (nb + i) * 16 + l15;
        #pragma unroll
        for (int r = 0; r < 4; ++r) {
            const int e = Ms * 16 + lg * 4 + r;
            const float v = accS[i][r];
            if (n < 64) silu_s[e * 72 + n] = f2bf(v * fsig(v));
            else        gat[e * 36 + (n - 64)] = fsig(v);
        }
    }
    __syncthreads();
    // gate vectors -> pv (bf16)
    #pragma unroll
    for (int i = 0; i < 3; ++i) {
        const int tv = 3 * w + i, Mv = tv >> 1, Nv = tv & 1;
        const int m = Mv >> 1, eb = (Mv & 1) * 16;
        const int u = Nv * 16 + l15;
        #pragma unroll
        for (int r = 0; r < 4; ++r) {
            const int e = eb + lg * 4 + r;
            pv_s[(m * 32 + e) * 40 + u] = f2bf(accV[i][r] * gat[e * 36 + u]);
        }
    }
    __syncthreads();

    // ---- linear (MFMA, B direct from L2) + fused atomic scatter
    {   // ls: [32,64] @ WlsT -> [32,96]
        const char* mls = wout + MLINS_OFF;
        f4 acc[3] = {{0.f,0.f,0.f,0.f},{0.f,0.f,0.f,0.f},{0.f,0.f,0.f,0.f}};
        #pragma unroll
        for (int k0 = 0; k0 < 2; ++k0) {
            const int kg = k0 * 32 + lg * 8;
            bf8 a = *(const bf8*)&silu_s[es_ * 72 + kg];
            #pragma unroll
            for (int i = 0; i < 3; ++i)
                acc[i] = mfma16(a, ldB(mls + ((nb + i) * 16 + l15) * 128 + kg * 2), acc[i]);
        }
        #pragma unroll
        for (int i = 0; i < 3; ++i) {
            const int n = (nb + i) * 16 + l15;
            #pragma unroll
            for (int r = 0; r < 4; ++r) {
                const int e = Ms * 16 + lg * 4 + r;
                atomicAdd(&agg[(size_t)row_sh[e] * 192 + n], acc[i][r]);
            }
        }
    }
    {   // lv: [96,32] @ WlvT -> [96,32]; rows rr -> (m = rr>>5, e = rr&31)
        const char* mlv = wout + MLINV_OFF;
        f4 acc[3] = {{0.f,0.f,0.f,0.f},{0.f,0.f,0.f,0.f},{0.f,0.f,0.f,0.f}};
        const int kg = lg * 8;
        BF a; int prevMv = -1;
        #pragma unroll
        for (int i = 0; i < 3; ++i) {
            const int tv = 3 * w + i, Mv = tv >> 1, Nv = tv & 1;
            if (Mv != prevMv) { prevMv = Mv; a.v = *(const bf8*)&pv_s[(Mv * 16 + l15) * 40 + kg]; }
            acc[i] = mfma16(a.v, ldB(mlv + (Nv * 16 + l15) * 64 + kg * 2), acc[i]);
        }
        #pragma unroll
        for (int i = 0; i < 3; ++i) {
            const int tv = 3 * w + i, Mv = tv >> 1, Nv = tv & 1;
            const int w2 = Nv * 16 + l15;
            #pragma unroll
            for (int r = 0; r < 4; ++r) {
                const int rr = Mv * 16 + lg * 4 + r;
                const int m = rr >> 5, e = rr & 31;
                atomicAdd(&agg[(size_t)row_sh[e] * 192 + 96 + w2 * 3 + m], acc[i][r]);
            }
        }
    }
}

// ================= update kernel: 32 nodes/block, 8 waves, K-split-2, no K-loop barriers ====
// Wave-group g computes K-half [g*half, (g+1)*half); partials reduced via LDS.
// Result (residual+delta) written into agg rows (cols 0..159).
__global__ __launch_bounds__(512, 4) void upd_kernel(
    const float* __restrict__ nf, const char* __restrict__ wout,
    float* __restrict__ agg)
{
    __shared__ float nf_sh[32 * 164];    // 20992B
    __shared__ float ag_sh[32 * 196];    // 25088B
    __shared__ float gat[32 * 36];       // 4608B
    __shared__ short silu_s[32 * 72];    // 4608B
    __shared__ short gv_s[96 * 40];      // 7680B
    __shared__ float red[3072];          // 12288B  -> total ~75.3KB => 2 blocks/CU

    const int t = threadIdx.x, w = t >> 6, lane = t & 63;
    const int g = w >> 2, wl = w & 3;              // K-half group, local wave
    const int l15 = lane & 15, lg = lane >> 4;
    const int nblk = blockIdx.x * 32;
    const char* W1 = wout + UPDW1_OFF;
    const char* W2 = wout + UPDW2_OFF;

    {   // stage node rows + agg rows (clamp tail)
        const int i = t >> 4, j = t & 15;
        int n = nblk + i; if (n > kNodes - 1) n = kNodes - 1;
        const float4* src = (const float4*)(nf + (size_t)n * 160);
        for (int c = j; c < 40; c += 16) *(float4*)&nf_sh[i * 164 + c * 4] = src[c];
        const float4* asrc = (const float4*)(agg + (size_t)n * 192);
        for (int c = j; c < 48; c += 16) *(float4*)&ag_sh[i * 196 + c * 4] = asrc[c];
    }
    __syncthreads();

    const int Ms = wl >> 1, nb = (wl & 1) * 3;
    const int es_ = Ms * 16 + l15;

    // ---- scalar K-loop: group g covers tiles [g*112, g*112+112). Region split at kt=192.
    f4 accS[3] = {{0.f,0.f,0.f,0.f},{0.f,0.f,0.f,0.f},{0.f,0.f,0.f,0.f}};
    {
        const int kt0 = g * 112, kt1 = kt0 + 112;
        const int ktSS = kt1 < 192 ? kt1 : 192;
        int kt = kt0;
        for (; kt < ktSS; ++kt) {                    // ss: A[j] = ns[u0+j] * agg_s[v]
            const char* wb = W1 + (size_t)kt * 6144;
            const int kp = kt * 32 + lg * 8;
            const int vv = kp >> 6, u0 = kp & 63;
            const float ys = ag_sh[es_ * 196 + vv];
            const float4 x0 = *(const float4*)&nf_sh[es_ * 164 + u0];
            const float4 x1 = *(const float4*)&nf_sh[es_ * 164 + u0 + 4];
            BF aS;
            aS.u[0] = pk2(x0.x * ys, x0.y * ys);
            aS.u[1] = pk2(x0.z * ys, x0.w * ys);
            aS.u[2] = pk2(x1.x * ys, x1.y * ys);
            aS.u[3] = pk2(x1.z * ys, x1.w * ys);
            #pragma unroll
            for (int i = 0; i < 3; ++i)
                accS[i] = mfma16(aS.v, ldB(wb + ((nb + i) * 16 + l15) * 64 + lg * 16), accS[i]);
        }
        for (; kt < kt1; ++kt) {                     // vv: A[j] = dot(nv[u0+j], agg_v[v])
            const char* wb = W1 + (size_t)kt * 6144;
            const int rp = kt * 32 + lg * 8 - 6144;
            const int vv = rp >> 5, u0 = rp & 31;
            const float* xp = &nf_sh[es_ * 164 + 64 + 3 * u0];
            const float* gp = &ag_sh[es_ * 196 + 96 + 3 * vv];
            const float g0 = gp[0], g1 = gp[1], g2 = gp[2];
            BF aS;
            #pragma unroll
            for (int j = 0; j < 4; ++j) {
                float a0 = xp[6*j  ] * g0 + xp[6*j+1] * g1 + xp[6*j+2] * g2;
                float a1 = xp[6*j+3] * g0 + xp[6*j+4] * g1 + xp[6*j+5] * g2;
                aS.u[j] = pk2(a0, a1);
            }
            #pragma unroll
            for (int i = 0; i < 3; ++i)
                accS[i] = mfma16(aS.v, ldB(wb + ((nb + i) * 16 + l15) * 64 + lg * 16), accS[i]);
        }
    }

    // ---- scalar reduce (group1 -> LDS, group0 adds) + silu/gate epilogue
    if (g == 1) {
        #pragma unroll
        for (int i = 0; i < 3; ++i) {
            const int n = (nb + i) * 16 + l15;
            #pragma unroll
            for (int r = 0; r < 4; ++r)
                red[(Ms * 16 + lg * 4 + r) * 96 + n] = accS[i][r];
        }
    }
    __syncthreads();
    if (g == 0) {
        #pragma unroll
        for (int i = 0; i < 3; ++i) {
            const int n = (nb + i) * 16 + l15;
            #pragma unroll
            for (int r = 0; r < 4; ++r) {
                const int e = Ms * 16 + lg * 4 + r;
                const float v = accS[i][r] + red[e * 96 + n];
                if (n < 64) silu_s[e * 72 + n] = f2bf(v * fsig(v));
                else        gat[e * 36 + (n - 64)] = fsig(v);
            }
        }
    }
    __syncthreads();                                 // redS consumed before redV reuse

    // ---- vector K-loop: group g covers tiles [g*80, g*80+80). Region split at kt=64.
    f4 accV[3] = {{0.f,0.f,0.f,0.f},{0.f,0.f,0.f,0.f},{0.f,0.f,0.f,0.f}};
    {
        const int kt0 = g * 80, kt1 = kt0 + 80;
        const int ktSV = kt1 < 64 ? kt1 : 64;
        int kt = kt0;
        for (; kt < ktSV; ++kt) {                    // sv: A[j] = ns[u0+j] * agg_v[v][m]
            const char* wb = W2 + (size_t)kt * 2048;
            BF aV; int prevMv = -1;
            #pragma unroll
            for (int i = 0; i < 3; ++i) {
                const int tv = 3 * wl + i, Mv = tv >> 1, Nv = tv & 1;
                if (Mv != prevMv) {
                    prevMv = Mv;
                    const int m = Mv >> 1, ev = (Mv & 1) * 16 + l15;
                    const int kp = kt * 32 + lg * 8;
                    const int vv = kp >> 6, u0 = kp & 63;
                    const float ym = ag_sh[ev * 196 + 96 + 3 * vv + m];
                    const float4 x0 = *(const float4*)&nf_sh[ev * 164 + u0];
                    const float4 x1 = *(const float4*)&nf_sh[ev * 164 + u0 + 4];
                    aV.u[0] = pk2(x0.x * ym, x0.y * ym);
                    aV.u[1] = pk2(x0.z * ym, x0.w * ym);
                    aV.u[2] = pk2(x1.x * ym, x1.y * ym);
                    aV.u[3] = pk2(x1.z * ym, x1.w * ym);
                }
                accV[i] = mfma16(aV.v, ldB(wb + (Nv * 16 + l15) * 64 + lg * 16), accV[i]);
            }
        }
        for (; kt < kt1; ++kt) {                     // vs: A[j] = nv[u][m] * agg_s[v0+j]
            const char* wb = W2 + (size_t)kt * 2048;
            BF aV; int prevMv = -1;
            #pragma unroll
            for (int i = 0; i < 3; ++i) {
                const int tv = 3 * wl + i, Mv = tv >> 1, Nv = tv & 1;
                if (Mv != prevMv) {
                    prevMv = Mv;
                    const int m = Mv >> 1, ev = (Mv & 1) * 16 + l15;
                    const int rp = kt * 32 + lg * 8 - 2048;
                    const int u = rp / 96, v0 = rp - u * 96;
                    const float xm = nf_sh[ev * 164 + 64 + 3 * u + m];
                    const float4 y0 = *(const float4*)&ag_sh[ev * 196 + v0];
                    const float4 y1 = *(const float4*)&ag_sh[ev * 196 + v0 + 4];
                    aV.u[0] = pk2(xm * y0.x, xm * y0.y);
                    aV.u[1] = pk2(xm * y0.z, xm * y0.w);
                    aV.u[2] = pk2(xm * y1.x, xm * y1.y);
                    aV.u[3] = pk2(xm * y1.z, xm * y1.w);
                }
                accV[i] = mfma16(aV.v, ldB(wb + (Nv * 16 + l15) * 64 + lg * 16), accV[i]);
            }
        }
    }

    // ---- vector reduce (group1 -> LDS, group0 adds) + gate -> gv
    if (g == 1) {
        #pragma unroll
        for (int i = 0; i < 3; ++i) {
            const int tv = 3 * wl + i, Mv = tv >> 1, Nv = tv & 1;
            #pragma unroll
            for (int r = 0; r < 4; ++r)
                red[(Mv * 16 + lg * 4 + r) * 32 + Nv * 16 + l15] = accV[i][r];
        }
    }
    __syncthreads();
    if (g == 0) {
        #pragma unroll
        for (int i = 0; i < 3; ++i) {
            const int tv = 3 * wl + i, Mv = tv >> 1, Nv = tv & 1;
            const int m = Mv >> 1, eb = (Mv & 1) * 16;
            const int u = Nv * 16 + l15;
            #pragma unroll
            for (int r = 0; r < 4; ++r) {
                const int e = eb + lg * 4 + r;
                const float v = accV[i][r] + red[(Mv * 16 + lg * 4 + r) * 32 + u];
                gv_s[(m * 32 + e) * 40 + u] = f2bf(v * gat[e * 36 + u]);
            }
        }
    }
    __syncthreads();

    // ---- final linears (MFMA, B direct from L2) + residual -> agg cols 0..159; group 0 only
    const int nvalid = kNodes - nblk;
    if (g == 0) {
        {   // ds: [32,64] @ WlsT_u -> [32,64]; 2 N-tiles per wave
            const char* uls = wout + ULINS_OFF;
            f4 acc[2] = {{0.f,0.f,0.f,0.f},{0.f,0.f,0.f,0.f}};
            const int nb2 = (wl & 1) * 2;
            #pragma unroll
            for (int k0 = 0; k0 < 2; ++k0) {
                const int kg = k0 * 32 + lg * 8;
                bf8 a = *(const bf8*)&silu_s[es_ * 72 + kg];
                #pragma unroll
                for (int i = 0; i < 2; ++i)
                    acc[i] = mfma16(a, ldB(uls + ((nb2 + i) * 16 + l15) * 128 + kg * 2), acc[i]);
            }
            #pragma unroll
            for (int i = 0; i < 2; ++i) {
                const int n = (nb2 + i) * 16 + l15;
                #pragma unroll
                for (int r = 0; r < 4; ++r) {
                    const int e = Ms * 16 + lg * 4 + r;
                    if (e < nvalid)
                        agg[(size_t)(nblk + e) * 192 + n] = nf_sh[e * 164 + n] + acc[i][r];
                }
            }
        }
        {   // dv: [96,32] @ WlvT_u -> [96,32]
            const char* ulv = wout + ULINV_OFF;
            f4 acc[3] = {{0.f,0.f,0.f,0.f},{0.f,0.f,0.f,0.f},{0.f,0.f,0.f,0.f}};
            const int kg = lg * 8;
            BF a; int prevMv = -1;
            #pragma unroll
            for (int i = 0; i < 3; ++i) {
                const int tv = 3 * wl + i, Mv = tv >> 1, Nv = tv & 1;
                if (Mv != prevMv) { prevMv = Mv; a.v = *(const bf8*)&gv_s[(Mv * 16 + l15) * 40 + kg]; }
                acc[i] = mfma16(a.v, ldB(ulv + (Nv * 16 + l15) * 64 + kg * 2), acc[i]);
            }
            #pragma unroll
            for (int i = 0; i < 3; ++i) {
                const int tv = 3 * wl + i, Mv = tv >> 1, Nv = tv & 1;
                const int w2 = Nv * 16 + l15;
                #pragma unroll
                for (int r = 0; r < 4; ++r) {
                    const int rr = Mv * 16 + lg * 4 + r;
                    const int m = rr >> 5, e = rr & 31;
                    if (e < nvalid)
                        agg[(size_t)(nblk + e) * 192 + 64 + w2 * 3 + m]
                            = nf_sh[e * 164 + 64 + w2 * 3 + m] + acc[i][r];
                }
            }
        }
    }
}

// ================= final copy: agg rows (cols 0..159) -> d_out [10000][160] ==========
__global__ __launch_bounds__(256) void copy_kernel(const float* __restrict__ agg,
                                                   float* __restrict__ out)
{
    int i = blockIdx.x * 256 + threadIdx.x;       // i indexes [10000][40] float4s
    if (i < 400000) {
        int n = i / 40, c = i - n * 40;
        ((float4*)out)[i] = ((const float4*)agg)[n * 48 + c];
    }
}

extern "C" void kernel_launch(void* const* d_in, const int* in_sizes, int n_in,
                              void* d_out, int out_size, void* d_ws, size_t ws_size,
                              hipStream_t stream) {
    const float* nf   = (const float*)d_in[0];
    const float* ea   = (const float*)d_in[1];
    const int*   eidx = (const int*)d_in[14];
    float* agg = (float*)d_ws;                     // f32 [10000][192] — ONLY ws use
    char*  wout = (char*)d_out;                    // weights live here until final copy

    hipMemsetAsync(agg, 0, 7680000, stream);
    prep_kernel<<<3760, 256, 0, stream>>>(
        (const float*)d_in[2], (const float*)d_in[3], (const float*)d_in[4],
        (const float*)d_in[5], (const float*)d_in[6], (const float*)d_in[7],
        (const float*)d_in[8], (const float*)d_in[9], (const float*)d_in[10],
        (const float*)d_in[11], (const float*)d_in[12], (const float*)d_in[13], wout);
    msg_kernel<<<kEdges / 32, 256, 0, stream>>>(nf, ea, eidx, wout, agg);
    upd_kernel<<<(kNodes + 31) / 32, 512, 0, stream>>>(nf, wout, agg);
    copy_kernel<<<1563, 256, 0, stream>>>(agg, (float*)d_out);
}